// Round 1
// baseline (557.327 us; speedup 1.0000x reference)
//
#include <hip/hip_runtime.h>

typedef __attribute__((ext_vector_type(8))) short s8v;
typedef __attribute__((ext_vector_type(4))) short s4v;
typedef __attribute__((ext_vector_type(4))) float f4v;

__device__ __forceinline__ short f2bf(float f){
  union { float f; unsigned u; } v; v.f = f;
  unsigned r = v.u + 0x7fffu + ((v.u >> 16) & 1u);
  return (short)(r >> 16);
}
__device__ __forceinline__ float bf2f(short s){
  union { unsigned u; float f; } v; v.u = ((unsigned)(unsigned short)s) << 16; return v.f;
}

// ---------------- elementwise fp32 -> bf16 ----------------
__global__ __launch_bounds__(256) void cvt_bf16_k(const float* __restrict__ in, short* __restrict__ out, int n4){
  int i = blockIdx.x*256 + threadIdx.x;
  if (i < n4){
    f4v v = ((const f4v*)in)[i];
    s4v o; o[0]=f2bf(v[0]); o[1]=f2bf(v[1]); o[2]=f2bf(v[2]); o[3]=f2bf(v[3]);
    ((s4v*)out)[i] = o;
  }
}

// ---------------- 1024x1024 fp32 -> bf16 transpose (for W^T) ----------------
__global__ __launch_bounds__(256) void transpose_w_k(const float* __restrict__ in, short* __restrict__ out){
  __shared__ float t[64][65];
  int c0 = blockIdx.x*64, r0 = blockIdx.y*64;
  int tx = threadIdx.x & 63, ty = threadIdx.x >> 6;
  #pragma unroll
  for (int i=0;i<16;i++){ int r = ty + i*4; t[r][tx] = in[(size_t)(r0+r)*1024 + c0+tx]; }
  __syncthreads();
  #pragma unroll
  for (int i=0;i<16;i++){ int cc = ty + i*4; out[(size_t)(c0+cc)*1024 + r0+tx] = f2bf(t[tx][cc]); }
}

// ---------------- bf16 MFMA GEMM: C[2048][1024] f32 = A[2048][1024] @ Bt[1024][1024]^T + bias ----------------
__global__ __launch_bounds__(256) void gemm_bf16_k(const short* __restrict__ A, const short* __restrict__ Bt,
                                                   const float* __restrict__ bias, float* __restrict__ C){
  const int K = 1024, N = 1024;
  __shared__ short As[64][72];
  __shared__ short Bs[64][72];
  int m0 = blockIdx.y*64, n0 = blockIdx.x*64;
  int lane = threadIdx.x & 63, wave = threadIdx.x >> 6;
  int wr = wave >> 1, wc = wave & 1;
  int g = lane >> 4, c = lane & 15;
  f4v acc[2][2] = {};
  int trow = threadIdx.x >> 3, tcol = (threadIdx.x & 7)*8;
  for (int k0 = 0; k0 < K; k0 += 64){
    #pragma unroll
    for (int p=0;p<2;p++){
      int r = trow + p*32;
      *(s8v*)(&As[r][tcol]) = *(const s8v*)(A + (size_t)(m0+r)*K + k0 + tcol);
      *(s8v*)(&Bs[r][tcol]) = *(const s8v*)(Bt + (size_t)(n0+r)*K + k0 + tcol);
    }
    __syncthreads();
    #pragma unroll
    for (int ks=0;ks<2;ks++){
      s8v a0 = *(const s8v*)(&As[wr*32 + c][ks*32 + g*8]);
      s8v a1 = *(const s8v*)(&As[wr*32 + 16 + c][ks*32 + g*8]);
      s8v b0 = *(const s8v*)(&Bs[wc*32 + c][ks*32 + g*8]);
      s8v b1 = *(const s8v*)(&Bs[wc*32 + 16 + c][ks*32 + g*8]);
      acc[0][0] = __builtin_amdgcn_mfma_f32_16x16x32_bf16(a0,b0,acc[0][0],0,0,0);
      acc[0][1] = __builtin_amdgcn_mfma_f32_16x16x32_bf16(a0,b1,acc[0][1],0,0,0);
      acc[1][0] = __builtin_amdgcn_mfma_f32_16x16x32_bf16(a1,b0,acc[1][0],0,0,0);
      acc[1][1] = __builtin_amdgcn_mfma_f32_16x16x32_bf16(a1,b1,acc[1][1],0,0,0);
    }
    __syncthreads();
  }
  #pragma unroll
  for (int rf=0;rf<2;rf++)
    #pragma unroll
    for (int cf=0;cf<2;cf++)
      #pragma unroll
      for (int i=0;i<4;i++){
        int row = m0 + wr*32 + rf*16 + g*4 + i;
        int col = n0 + wc*32 + cf*16 + c;
        C[(size_t)row*N + col] = acc[rf][cf][i] + bias[col];
      }
}

// ---------------- RoPE + scale + head-major bf16 layout ----------------
__global__ __launch_bounds__(256) void rope_qk_k(const float* __restrict__ Q, const float* __restrict__ Kf,
                                                 const float* __restrict__ cs, const float* __restrict__ sn,
                                                 short* __restrict__ Qb, short* __restrict__ Kb){
  int idx = blockIdx.x*256 + threadIdx.x;      // over B*S*H*32 = 1M pairs
  int i = idx & 31, h = (idx>>5) & 15, s = (idx>>9) & 1023, b = idx >> 19;
  float co = cs[s*32+i], si = sn[s*32+i];
  size_t src = ((size_t)(b*1024+s))*1024 + h*64 + 2*i;
  size_t dst = ((size_t)((b*16+h)*1024 + s))*64 + 2*i;
  float qe = Q[src], qo = Q[src+1];
  const float scl = 0.125f;
  Qb[dst]   = f2bf((qe*co - qo*si)*scl);
  Qb[dst+1] = f2bf((qe*si + qo*co)*scl);
  float ke = Kf[src], ko = Kf[src+1];
  Kb[dst]   = f2bf(ke*co - ko*si);
  Kb[dst+1] = f2bf(ke*si + ko*co);
}

// ---------------- V -> V^T per head, bf16 ----------------
__global__ __launch_bounds__(256) void v_transpose_k(const float* __restrict__ V, short* __restrict__ Vt){
  __shared__ float t[64][65];
  int s0 = blockIdx.x*64; int h = blockIdx.y; int b = blockIdx.z;
  int tx = threadIdx.x & 63, ty = threadIdx.x >> 6;
  #pragma unroll
  for (int i=0;i<16;i++){ int r = ty + i*4; t[r][tx] = V[((size_t)(b*1024+s0+r))*1024 + h*64 + tx]; }
  __syncthreads();
  size_t base = ((size_t)(b*16+h))*65536;
  #pragma unroll
  for (int i=0;i<16;i++){ int d = ty + i*4; Vt[base + (size_t)d*1024 + s0 + tx] = f2bf(t[tx][d]); }
}

// ---------------- scores + rel bias + entmax1.5 -> attn bf16, bucket weights ----------------
#define SPAD 1028
__global__ __launch_bounds__(256) void attn_scores_k(const short* __restrict__ Qb, const short* __restrict__ Kb,
                                                     const float* __restrict__ rel, short* __restrict__ attnG,
                                                     float* __restrict__ wbuck){
  __shared__ float sc[32*SPAD];    // 128.5 KB
  __shared__ float pb[32][65];     // 8.3 KB
  __shared__ float wrow[4][66];
  int lane = threadIdx.x & 63, wave = threadIdx.x >> 6;
  int g = lane >> 4, c = lane & 15;
  int bh = blockIdx.y, q0 = blockIdx.x*32;
  const short* Qh = Qb + (size_t)bh*65536;
  const short* Kh = Kb + (size_t)bh*65536;

  // Q fragments for this q-tile (rows q0..q0+31, d=0..63)
  s8v qa[2][2];
  #pragma unroll
  for (int rf=0;rf<2;rf++)
    #pragma unroll
    for (int ks=0;ks<2;ks++)
      qa[rf][ks] = *(const s8v*)(Qh + (q0 + rf*16 + c)*64 + ks*32 + g*8);

  // p[r][j] = q_row(r) . rel_emb[j]
  for (int e = threadIdx.x; e < 32*65; e += 256){
    int r = e/65, j = e - r*65;
    const short* qrow = Qh + (q0+r)*64;
    const float* rrow = rel + j*64;
    float s = 0.f;
    #pragma unroll
    for (int d=0; d<64; d++) s += bf2f(qrow[d])*rrow[d];
    pb[r][j] = s;
  }

  // scores tile: wave covers cols [wave*256, +256)
  int kc0 = wave*256;
  for (int ct=0; ct<16; ct++){
    const short* kp = Kh + (kc0 + ct*16 + c)*64 + g*8;
    s8v b0 = *(const s8v*)(kp);
    s8v b1 = *(const s8v*)(kp + 32);
    f4v a0 = {}, a1 = {};
    a0 = __builtin_amdgcn_mfma_f32_16x16x32_bf16(qa[0][0], b0, a0, 0,0,0);
    a0 = __builtin_amdgcn_mfma_f32_16x16x32_bf16(qa[0][1], b1, a0, 0,0,0);
    a1 = __builtin_amdgcn_mfma_f32_16x16x32_bf16(qa[1][0], b0, a1, 0,0,0);
    a1 = __builtin_amdgcn_mfma_f32_16x16x32_bf16(qa[1][1], b1, a1, 0,0,0);
    int col = kc0 + ct*16 + c;
    #pragma unroll
    for (int i=0;i<4;i++){
      sc[(g*4+i)*SPAD + col]    = a0[i];
      sc[(16+g*4+i)*SPAD + col] = a1[i];
    }
  }
  __syncthreads();

  // entmax per row (wave w owns rows w*8 .. w*8+7)
  for (int rr=0; rr<8; rr++){
    int r = wave*8 + rr;
    int qg = q0 + r;
    float x[16];
    float mx = -1e30f;
    #pragma unroll
    for (int i=0;i<16;i++){
      int col = lane + i*64;
      int dlt = col - qg;
      int j = min(max(dlt,-32),32) + 32;
      float v = sc[r*SPAD + col] + pb[r][j];
      x[i] = v; mx = fmaxf(mx, v);
    }
    #pragma unroll
    for (int o=32;o>0;o>>=1) mx = fmaxf(mx, __shfl_xor(mx, o, 64));
    #pragma unroll
    for (int i=0;i<16;i++) x[i] = (x[i]-mx)*0.5f;
    // bisection for tau in [-1, 0]: f(tau) = sum((x-tau)_+^2) - 1, decreasing
    float lo = -1.0f, hi = 0.0f;
    for (int it=0; it<24; it++){
      float mid = 0.5f*(lo+hi);
      float ss = 0.f;
      #pragma unroll
      for (int i=0;i<16;i++){ float t = x[i]-mid; t = fmaxf(t,0.f); ss += t*t; }
      #pragma unroll
      for (int o=32;o>0;o>>=1) ss += __shfl_xor(ss, o, 64);
      if (ss >= 1.0f) lo = mid; else hi = mid;
    }
    float tau = 0.5f*(lo+hi);
    for (int j=lane; j<65; j+=64) wrow[wave][j] = 0.f;
    __syncthreads();
    float av[16]; float w0 = 0.f, w64v = 0.f;
    #pragma unroll
    for (int i=0;i<16;i++){
      int col = lane + i*64;
      float t = fmaxf(x[i]-tau, 0.f);
      float a = t*t; av[i] = a;
      int raw = col - qg;
      if (raw <= -32) w0 += a;
      else if (raw >= 32) w64v += a;
      else wrow[wave][raw+32] = a;   // unique (row,col) owner -> no race
    }
    #pragma unroll
    for (int o=32;o>0;o>>=1){ w0 += __shfl_xor(w0,o,64); w64v += __shfl_xor(w64v,o,64); }
    if (lane == 0){ wrow[wave][0] = w0; wrow[wave][64] = w64v; }
    __syncthreads();
    size_t wbase = ((size_t)bh*1024 + qg)*65;
    for (int j=lane; j<65; j+=64) wbuck[wbase+j] = wrow[wave][j];
    size_t abase = ((size_t)bh*1024 + qg)*1024;
    #pragma unroll
    for (int i=0;i<16;i++) attnG[abase + lane + i*64] = f2bf(av[i]);
  }
}

// ---------------- PV + rel-ctx -> ctx bf16 [B*S][H*DH] ----------------
__global__ __launch_bounds__(256) void attn_pv_k(const short* __restrict__ attnG, const short* __restrict__ Vt,
                                                 const float* __restrict__ wbuck, const float* __restrict__ rel,
                                                 short* __restrict__ ctxb){
  __shared__ float part[4][32][64];
  __shared__ float wb[32][65];
  __shared__ float rl[65*64];
  int lane = threadIdx.x & 63, wave = threadIdx.x >> 6;
  int g = lane >> 4, c = lane & 15;
  int bh = blockIdx.y, q0 = blockIdx.x*32;
  const short* Ah = attnG + ((size_t)bh*1024 + q0)*1024;
  const short* Vh = Vt + (size_t)bh*65536;
  for (int e = threadIdx.x; e < 65*64; e += 256) rl[e] = rel[e];
  const float* wsrc = wbuck + ((size_t)bh*1024 + q0)*65;
  for (int e = threadIdx.x; e < 32*65; e += 256) ((float*)wb)[e] = wsrc[e];

  f4v acc[2][4] = {};
  int kc0 = wave*256;
  for (int kk=0; kk<8; kk++){
    int kb = kc0 + kk*32 + g*8;
    s8v a0 = *(const s8v*)(Ah + (size_t)c*1024 + kb);
    s8v a1 = *(const s8v*)(Ah + (size_t)(16+c)*1024 + kb);
    #pragma unroll
    for (int ct=0; ct<4; ct++){
      s8v bv = *(const s8v*)(Vh + (size_t)(ct*16+c)*1024 + kb);
      acc[0][ct] = __builtin_amdgcn_mfma_f32_16x16x32_bf16(a0, bv, acc[0][ct],0,0,0);
      acc[1][ct] = __builtin_amdgcn_mfma_f32_16x16x32_bf16(a1, bv, acc[1][ct],0,0,0);
    }
  }
  #pragma unroll
  for (int rf=0;rf<2;rf++)
    #pragma unroll
    for (int ct=0;ct<4;ct++)
      #pragma unroll
      for (int i=0;i<4;i++)
        part[wave][rf*16 + g*4 + i][ct*16 + c] = acc[rf][ct][i];
  __syncthreads();
  int b = bh >> 4, h = bh & 15;
  for (int e = threadIdx.x; e < 2048; e += 256){
    int r = e >> 6, d = e & 63;
    float s = part[0][r][d] + part[1][r][d] + part[2][r][d] + part[3][r][d];
    #pragma unroll
    for (int j=0;j<65;j++) s += wb[r][j]*rl[j*64+d];
    ctxb[((size_t)(b*1024 + q0 + r))*1024 + h*64 + d] = f2bf(s);
  }
}

extern "C" void kernel_launch(void* const* d_in, const int* in_sizes, int n_in,
                              void* d_out, int out_size, void* d_ws, size_t ws_size,
                              hipStream_t stream) {
  (void)in_sizes; (void)n_in; (void)out_size; (void)ws_size;
  const float* x    = (const float*)d_in[0];
  const float* w_q  = (const float*)d_in[1];
  const float* b_q  = (const float*)d_in[2];
  const float* w_k  = (const float*)d_in[3];
  const float* b_k  = (const float*)d_in[4];
  const float* w_v  = (const float*)d_in[5];
  const float* b_v  = (const float*)d_in[6];
  const float* w_o  = (const float*)d_in[7];
  const float* b_o  = (const float*)d_in[8];
  const float* rel  = (const float*)d_in[9];
  const float* rcos = (const float*)d_in[10];
  const float* rsin = (const float*)d_in[11];
  float* out = (float*)d_out;

  char* w = (char*)d_ws;
  short* xb    = (short*)(w);                        // 4 MiB
  short* wqT   = (short*)(w + ((size_t)4<<20));      // 2 MiB each
  short* wkT   = (short*)(w + ((size_t)6<<20));
  short* wvT   = (short*)(w + ((size_t)8<<20));
  short* woT   = (short*)(w + ((size_t)10<<20));
  float* Qf    = (float*)(w + ((size_t)12<<20));     // 8 MiB each
  float* Kf    = (float*)(w + ((size_t)20<<20));
  float* Vf    = (float*)(w + ((size_t)28<<20));
  short* Qb    = (short*)(w + ((size_t)36<<20));     // 4 MiB each
  short* Kb    = (short*)(w + ((size_t)40<<20));
  short* Vt    = (short*)(w + ((size_t)44<<20));
  short* ctxb  = (short*)(w + ((size_t)48<<20));     // 4 MiB
  float* wbuck = (float*)(w + ((size_t)52<<20));     // 8.2 MiB
  short* attnG = (short*)(w + ((size_t)62<<20));     // 64 MiB

  cvt_bf16_k<<<2048, 256, 0, stream>>>(x, xb, 524288);
  transpose_w_k<<<dim3(16,16), 256, 0, stream>>>(w_q, wqT);
  transpose_w_k<<<dim3(16,16), 256, 0, stream>>>(w_k, wkT);
  transpose_w_k<<<dim3(16,16), 256, 0, stream>>>(w_v, wvT);
  transpose_w_k<<<dim3(16,16), 256, 0, stream>>>(w_o, woT);
  gemm_bf16_k<<<dim3(16,32), 256, 0, stream>>>(xb, wqT, b_q, Qf);
  gemm_bf16_k<<<dim3(16,32), 256, 0, stream>>>(xb, wkT, b_k, Kf);
  gemm_bf16_k<<<dim3(16,32), 256, 0, stream>>>(xb, wvT, b_v, Vf);
  rope_qk_k<<<4096, 256, 0, stream>>>(Qf, Kf, rcos, rsin, Qb, Kb);
  v_transpose_k<<<dim3(16,16,2), 256, 0, stream>>>(Vf, Vt);
  attn_scores_k<<<dim3(32,32), 256, 0, stream>>>(Qb, Kb, rel, attnG, wbuck);
  attn_pv_k<<<dim3(32,32), 256, 0, stream>>>(attnG, Vt, wbuck, rel, ctxb);
  gemm_bf16_k<<<dim3(16,32), 256, 0, stream>>>(ctxb, woT, b_o, out);
}

// Round 2
// 323.010 us; speedup vs baseline: 1.7254x; 1.7254x over previous
//
#include <hip/hip_runtime.h>

typedef __attribute__((ext_vector_type(8))) short s8v;
typedef __attribute__((ext_vector_type(4))) short s4v;
typedef __attribute__((ext_vector_type(4))) float f4v;

__device__ __forceinline__ short f2bf(float f){
  union { float f; unsigned u; } v; v.f = f;
  unsigned r = v.u + 0x7fffu + ((v.u >> 16) & 1u);
  return (short)(r >> 16);
}
__device__ __forceinline__ float bf2f(short s){
  union { unsigned u; float f; } v; v.u = ((unsigned)(unsigned short)s) << 16; return v.f;
}

// ---------------- elementwise fp32 -> bf16 ----------------
__global__ __launch_bounds__(256) void cvt_bf16_k(const float* __restrict__ in, short* __restrict__ out, int n4){
  int i = blockIdx.x*256 + threadIdx.x;
  if (i < n4){
    f4v v = ((const f4v*)in)[i];
    s4v o; o[0]=f2bf(v[0]); o[1]=f2bf(v[1]); o[2]=f2bf(v[2]); o[3]=f2bf(v[3]);
    ((s4v*)out)[i] = o;
  }
}

// ---------------- 1024x1024 fp32 -> bf16 transpose (for W^T) ----------------
__global__ __launch_bounds__(256) void transpose_w_k(const float* __restrict__ in, short* __restrict__ out){
  __shared__ float t[64][65];
  int c0 = blockIdx.x*64, r0 = blockIdx.y*64;
  int tx = threadIdx.x & 63, ty = threadIdx.x >> 6;
  #pragma unroll
  for (int i=0;i<16;i++){ int r = ty + i*4; t[r][tx] = in[(size_t)(r0+r)*1024 + c0+tx]; }
  __syncthreads();
  #pragma unroll
  for (int i=0;i<16;i++){ int cc = ty + i*4; out[(size_t)(c0+cc)*1024 + r0+tx] = f2bf(t[tx][cc]); }
}

// ---------------- bf16 MFMA GEMM: C[2048][1024] f32 = A[2048][1024] @ Bt[1024][1024]^T + bias ----------------
__global__ __launch_bounds__(256) void gemm_bf16_k(const short* __restrict__ A, const short* __restrict__ Bt,
                                                   const float* __restrict__ bias, float* __restrict__ C){
  const int K = 1024, N = 1024;
  __shared__ short As[64][72];
  __shared__ short Bs[64][72];
  int m0 = blockIdx.y*64, n0 = blockIdx.x*64;
  int lane = threadIdx.x & 63, wave = threadIdx.x >> 6;
  int wr = wave >> 1, wc = wave & 1;
  int g = lane >> 4, c = lane & 15;
  f4v acc[2][2] = {};
  int trow = threadIdx.x >> 3, tcol = (threadIdx.x & 7)*8;
  for (int k0 = 0; k0 < K; k0 += 64){
    #pragma unroll
    for (int p=0;p<2;p++){
      int r = trow + p*32;
      *(s8v*)(&As[r][tcol]) = *(const s8v*)(A + (size_t)(m0+r)*K + k0 + tcol);
      *(s8v*)(&Bs[r][tcol]) = *(const s8v*)(Bt + (size_t)(n0+r)*K + k0 + tcol);
    }
    __syncthreads();
    #pragma unroll
    for (int ks=0;ks<2;ks++){
      s8v a0 = *(const s8v*)(&As[wr*32 + c][ks*32 + g*8]);
      s8v a1 = *(const s8v*)(&As[wr*32 + 16 + c][ks*32 + g*8]);
      s8v b0 = *(const s8v*)(&Bs[wc*32 + c][ks*32 + g*8]);
      s8v b1 = *(const s8v*)(&Bs[wc*32 + 16 + c][ks*32 + g*8]);
      acc[0][0] = __builtin_amdgcn_mfma_f32_16x16x32_bf16(a0,b0,acc[0][0],0,0,0);
      acc[0][1] = __builtin_amdgcn_mfma_f32_16x16x32_bf16(a0,b1,acc[0][1],0,0,0);
      acc[1][0] = __builtin_amdgcn_mfma_f32_16x16x32_bf16(a1,b0,acc[1][0],0,0,0);
      acc[1][1] = __builtin_amdgcn_mfma_f32_16x16x32_bf16(a1,b1,acc[1][1],0,0,0);
    }
    __syncthreads();
  }
  #pragma unroll
  for (int rf=0;rf<2;rf++)
    #pragma unroll
    for (int cf=0;cf<2;cf++)
      #pragma unroll
      for (int i=0;i<4;i++){
        int row = m0 + wr*32 + rf*16 + g*4 + i;
        int col = n0 + wc*32 + cf*16 + c;
        C[(size_t)row*N + col] = acc[rf][cf][i] + bias[col];
      }
}

// ---------------- RoPE + scale + head-major bf16 layout ----------------
__global__ __launch_bounds__(256) void rope_qk_k(const float* __restrict__ Q, const float* __restrict__ Kf,
                                                 const float* __restrict__ cs, const float* __restrict__ sn,
                                                 short* __restrict__ Qb, short* __restrict__ Kb){
  int idx = blockIdx.x*256 + threadIdx.x;      // over B*S*H*32 = 1M pairs
  int i = idx & 31, h = (idx>>5) & 15, s = (idx>>9) & 1023, b = idx >> 19;
  float co = cs[s*32+i], si = sn[s*32+i];
  size_t src = ((size_t)(b*1024+s))*1024 + h*64 + 2*i;
  size_t dst = ((size_t)((b*16+h)*1024 + s))*64 + 2*i;
  float qe = Q[src], qo = Q[src+1];
  const float scl = 0.125f;
  Qb[dst]   = f2bf((qe*co - qo*si)*scl);
  Qb[dst+1] = f2bf((qe*si + qo*co)*scl);
  float ke = Kf[src], ko = Kf[src+1];
  Kb[dst]   = f2bf(ke*co - ko*si);
  Kb[dst+1] = f2bf(ke*si + ko*co);
}

// ---------------- V -> V^T per head, bf16 ----------------
__global__ __launch_bounds__(256) void v_transpose_k(const float* __restrict__ V, short* __restrict__ Vt){
  __shared__ float t[64][65];
  int s0 = blockIdx.x*64; int h = blockIdx.y; int b = blockIdx.z;
  int tx = threadIdx.x & 63, ty = threadIdx.x >> 6;
  #pragma unroll
  for (int i=0;i<16;i++){ int r = ty + i*4; t[r][tx] = V[((size_t)(b*1024+s0+r))*1024 + h*64 + tx]; }
  __syncthreads();
  size_t base = ((size_t)(b*16+h))*65536;
  #pragma unroll
  for (int i=0;i<16;i++){ int d = ty + i*4; Vt[base + (size_t)d*1024 + s0 + tx] = f2bf(t[tx][d]); }
}

// ---------------- scores + rel bias + entmax1.5 (Newton) -> attn bf16, bucket weights ----------------
#define SPAD 1028
__global__ __launch_bounds__(256) void attn_scores_k(const short* __restrict__ Qb, const short* __restrict__ Kb,
                                                     const short* __restrict__ relb, short* __restrict__ attnG,
                                                     float* __restrict__ wbuck){
  __shared__ float sc[16*SPAD];    // 64.3 KB
  __shared__ float pb[16][65];     // 4.2 KB
  __shared__ float wrow[16][66];   // 4.2 KB
  int lane = threadIdx.x & 63, wave = threadIdx.x >> 6;
  int g = lane >> 4, c = lane & 15;
  int bh = blockIdx.y, q0 = blockIdx.x*16;
  const short* Qh = Qb + (size_t)bh*65536;
  const short* Kh = Kb + (size_t)bh*65536;

  for (int e = threadIdx.x; e < 16*66; e += 256) ((float*)wrow)[e] = 0.f;

  // Q fragments (rows q0..q0+15, d=0..63)
  s8v qa[2];
  qa[0] = *(const s8v*)(Qh + (q0 + c)*64 + g*8);
  qa[1] = *(const s8v*)(Qh + (q0 + c)*64 + 32 + g*8);

  // pb[r][j] = q_row(r) . rel_emb[j] via MFMA; wave w does j-tile w, wave 3 also tile 4
  {
    int ntile = (wave==3) ? 2 : 1;
    for (int t=0; t<ntile; t++){
      int jt = (t==0) ? wave : 4;
      int j = jt*16 + c;
      s8v rb0 = {}, rb1 = {};
      if (j < 65){
        rb0 = *(const s8v*)(relb + j*64 + g*8);
        rb1 = *(const s8v*)(relb + j*64 + 32 + g*8);
      }
      f4v pa = {};
      pa = __builtin_amdgcn_mfma_f32_16x16x32_bf16(qa[0], rb0, pa, 0,0,0);
      pa = __builtin_amdgcn_mfma_f32_16x16x32_bf16(qa[1], rb1, pa, 0,0,0);
      if (j < 65){
        #pragma unroll
        for (int i=0;i<4;i++) pb[g*4+i][j] = pa[i];
      }
    }
  }

  // scores tile: wave covers cols [wave*256, +256)
  int kc0 = wave*256;
  for (int ct=0; ct<16; ct++){
    const short* kp = Kh + (kc0 + ct*16 + c)*64 + g*8;
    s8v b0 = *(const s8v*)(kp);
    s8v b1 = *(const s8v*)(kp + 32);
    f4v a0 = {};
    a0 = __builtin_amdgcn_mfma_f32_16x16x32_bf16(qa[0], b0, a0, 0,0,0);
    a0 = __builtin_amdgcn_mfma_f32_16x16x32_bf16(qa[1], b1, a0, 0,0,0);
    int col = kc0 + ct*16 + c;
    #pragma unroll
    for (int i=0;i<4;i++) sc[(g*4+i)*SPAD + col] = a0[i];
  }
  __syncthreads();

  // entmax per row; wave owns rows wave*4..+3, Newton chains interleaved for ILP
  float x[4][16], mx[4], tau[4];
  #pragma unroll
  for (int j=0;j<4;j++){
    int r = wave*4+j; int qg = q0+r;
    mx[j] = -1e30f;
    #pragma unroll
    for (int i=0;i<16;i++){
      int col = lane + i*64;
      int d = col - qg; int jj = min(max(d,-32),32)+32;
      float v = sc[r*SPAD+col] + pb[r][jj];
      x[j][i] = v; mx[j] = fmaxf(mx[j], v);
    }
  }
  #pragma unroll
  for (int o=32;o>0;o>>=1)
    #pragma unroll
    for (int j=0;j<4;j++) mx[j] = fmaxf(mx[j], __shfl_xor(mx[j],o,64));
  #pragma unroll
  for (int j=0;j<4;j++){
    #pragma unroll
    for (int i=0;i<16;i++) x[j][i] = (x[j][i]-mx[j])*0.5f;
    tau[j] = -1.0f;
  }
  // Newton on g(tau)=sum((x-tau)_+^2)-1: convex decreasing, tau0=-1 <= tau* -> monotone from below
  for (int it=0; it<8; it++){
    float S1[4], S2[4];
    #pragma unroll
    for (int j=0;j<4;j++){
      float s1=0.f, s2=0.f;
      #pragma unroll
      for (int i=0;i<16;i++){ float t = fmaxf(x[j][i]-tau[j], 0.f); s1 += t; s2 += t*t; }
      S1[j]=s1; S2[j]=s2;
    }
    #pragma unroll
    for (int o=32;o>0;o>>=1)
      #pragma unroll
      for (int j=0;j<4;j++){ S1[j]+=__shfl_xor(S1[j],o,64); S2[j]+=__shfl_xor(S2[j],o,64); }
    #pragma unroll
    for (int j=0;j<4;j++) tau[j] += (S2[j]-1.0f)/(2.0f*S1[j]);
  }

  // epilogue: attn out (bf16) + bucket weights
  float w0[4], w64v[4];
  #pragma unroll
  for (int j=0;j<4;j++){
    int r = wave*4+j; int qg = q0+r;
    float a0s=0.f, a64=0.f;
    size_t abase = ((size_t)bh*1024 + qg)*1024;
    #pragma unroll
    for (int i=0;i<16;i++){
      int col = lane + i*64;
      float t = fmaxf(x[j][i]-tau[j], 0.f); float a = t*t;
      attnG[abase+col] = f2bf(a);
      int raw = col - qg;
      if (raw <= -32) a0s += a;
      else if (raw >= 32) a64 += a;
      else wrow[r][raw+32] = a;   // unique (row,col) owner -> no race
    }
    w0[j]=a0s; w64v[j]=a64;
  }
  #pragma unroll
  for (int o=32;o>0;o>>=1)
    #pragma unroll
    for (int j=0;j<4;j++){ w0[j]+=__shfl_xor(w0[j],o,64); w64v[j]+=__shfl_xor(w64v[j],o,64); }
  if (lane==0){
    #pragma unroll
    for (int j=0;j<4;j++){ int r=wave*4+j; wrow[r][0]=w0[j]; wrow[r][64]=w64v[j]; }
  }
  __syncthreads();
  for (int e = threadIdx.x; e < 16*65; e += 256){
    int r = e/65, jj = e - r*65;
    wbuck[((size_t)bh*1024 + q0 + r)*65 + jj] = wrow[r][jj];
  }
}

// ---------------- PV + rel-ctx -> ctx bf16 [B*S][H*DH] ----------------
__global__ __launch_bounds__(256) void attn_pv_k(const short* __restrict__ attnG, const short* __restrict__ Vt,
                                                 const float* __restrict__ wbuck, const float* __restrict__ rel,
                                                 short* __restrict__ ctxb){
  __shared__ float part[4][32][64];
  __shared__ float wb[32][65];
  __shared__ float rl[65*64];
  int lane = threadIdx.x & 63, wave = threadIdx.x >> 6;
  int g = lane >> 4, c = lane & 15;
  int bh = blockIdx.y, q0 = blockIdx.x*32;
  const short* Ah = attnG + ((size_t)bh*1024 + q0)*1024;
  const short* Vh = Vt + (size_t)bh*65536;
  for (int e = threadIdx.x; e < 65*64; e += 256) rl[e] = rel[e];
  const float* wsrc = wbuck + ((size_t)bh*1024 + q0)*65;
  for (int e = threadIdx.x; e < 32*65; e += 256) ((float*)wb)[e] = wsrc[e];

  f4v acc[2][4] = {};
  int kc0 = wave*256;
  for (int kk=0; kk<8; kk++){
    int kb = kc0 + kk*32 + g*8;
    s8v a0 = *(const s8v*)(Ah + (size_t)c*1024 + kb);
    s8v a1 = *(const s8v*)(Ah + (size_t)(16+c)*1024 + kb);
    #pragma unroll
    for (int ct=0; ct<4; ct++){
      s8v bv = *(const s8v*)(Vh + (size_t)(ct*16+c)*1024 + kb);
      acc[0][ct] = __builtin_amdgcn_mfma_f32_16x16x32_bf16(a0, bv, acc[0][ct],0,0,0);
      acc[1][ct] = __builtin_amdgcn_mfma_f32_16x16x32_bf16(a1, bv, acc[1][ct],0,0,0);
    }
  }
  #pragma unroll
  for (int rf=0;rf<2;rf++)
    #pragma unroll
    for (int ct=0;ct<4;ct++)
      #pragma unroll
      for (int i=0;i<4;i++)
        part[wave][rf*16 + g*4 + i][ct*16 + c] = acc[rf][ct][i];
  __syncthreads();
  int b = bh >> 4, h = bh & 15;
  for (int e = threadIdx.x; e < 2048; e += 256){
    int r = e >> 6, d = e & 63;
    float s = part[0][r][d] + part[1][r][d] + part[2][r][d] + part[3][r][d];
    #pragma unroll
    for (int j=0;j<65;j++) s += wb[r][j]*rl[j*64+d];
    ctxb[((size_t)(b*1024 + q0 + r))*1024 + h*64 + d] = f2bf(s);
  }
}

extern "C" void kernel_launch(void* const* d_in, const int* in_sizes, int n_in,
                              void* d_out, int out_size, void* d_ws, size_t ws_size,
                              hipStream_t stream) {
  (void)in_sizes; (void)n_in; (void)out_size; (void)ws_size;
  const float* x    = (const float*)d_in[0];
  const float* w_q  = (const float*)d_in[1];
  const float* b_q  = (const float*)d_in[2];
  const float* w_k  = (const float*)d_in[3];
  const float* b_k  = (const float*)d_in[4];
  const float* w_v  = (const float*)d_in[5];
  const float* b_v  = (const float*)d_in[6];
  const float* w_o  = (const float*)d_in[7];
  const float* b_o  = (const float*)d_in[8];
  const float* rel  = (const float*)d_in[9];
  const float* rcos = (const float*)d_in[10];
  const float* rsin = (const float*)d_in[11];
  float* out = (float*)d_out;

  char* w = (char*)d_ws;
  short* xb    = (short*)(w);                        // 4 MiB
  short* wqT   = (short*)(w + ((size_t)4<<20));      // 2 MiB each
  short* wkT   = (short*)(w + ((size_t)6<<20));
  short* wvT   = (short*)(w + ((size_t)8<<20));
  short* woT   = (short*)(w + ((size_t)10<<20));
  float* Qf    = (float*)(w + ((size_t)12<<20));     // 8 MiB each
  float* Kf    = (float*)(w + ((size_t)20<<20));
  float* Vf    = (float*)(w + ((size_t)28<<20));
  short* Qb    = (short*)(w + ((size_t)36<<20));     // 4 MiB each
  short* Kb    = (short*)(w + ((size_t)40<<20));
  short* Vt    = (short*)(w + ((size_t)44<<20));
  short* ctxb  = (short*)(w + ((size_t)48<<20));     // 4 MiB
  float* wbuck = (float*)(w + ((size_t)52<<20));     // 8.2 MiB
  short* relb  = (short*)(w + ((size_t)61<<20));     // 8.3 KB
  short* attnG = (short*)(w + ((size_t)62<<20));     // 64 MiB

  cvt_bf16_k<<<2048, 256, 0, stream>>>(x, xb, 524288);
  cvt_bf16_k<<<5, 256, 0, stream>>>(rel, relb, 1040);
  transpose_w_k<<<dim3(16,16), 256, 0, stream>>>(w_q, wqT);
  transpose_w_k<<<dim3(16,16), 256, 0, stream>>>(w_k, wkT);
  transpose_w_k<<<dim3(16,16), 256, 0, stream>>>(w_v, wvT);
  transpose_w_k<<<dim3(16,16), 256, 0, stream>>>(w_o, woT);
  gemm_bf16_k<<<dim3(16,32), 256, 0, stream>>>(xb, wqT, b_q, Qf);
  gemm_bf16_k<<<dim3(16,32), 256, 0, stream>>>(xb, wkT, b_k, Kf);
  gemm_bf16_k<<<dim3(16,32), 256, 0, stream>>>(xb, wvT, b_v, Vf);
  rope_qk_k<<<4096, 256, 0, stream>>>(Qf, Kf, rcos, rsin, Qb, Kb);
  v_transpose_k<<<dim3(16,16,2), 256, 0, stream>>>(Vf, Vt);
  attn_scores_k<<<dim3(64,32), 256, 0, stream>>>(Qb, Kb, relb, attnG, wbuck);
  attn_pv_k<<<dim3(32,32), 256, 0, stream>>>(attnG, Vt, wbuck, rel, ctxb);
  gemm_bf16_k<<<dim3(16,32), 256, 0, stream>>>(ctxb, woT, b_o, out);
}

// Round 3
// 294.871 us; speedup vs baseline: 1.8901x; 1.0954x over previous
//
#include <hip/hip_runtime.h>

typedef __attribute__((ext_vector_type(8))) short s8v;
typedef __attribute__((ext_vector_type(4))) short s4v;
typedef __attribute__((ext_vector_type(4))) float f4v;

__device__ __forceinline__ short f2bf(float f){
  union { float f; unsigned u; } v; v.f = f;
  unsigned r = v.u + 0x7fffu + ((v.u >> 16) & 1u);
  return (short)(r >> 16);
}
__device__ __forceinline__ float bf2f(short s){
  union { unsigned u; float f; } v; v.u = ((unsigned)(unsigned short)s) << 16; return v.f;
}

// ---------------- elementwise fp32 -> bf16 ----------------
__global__ __launch_bounds__(256) void cvt_bf16_k(const float* __restrict__ in, short* __restrict__ out, int n4){
  int i = blockIdx.x*256 + threadIdx.x;
  if (i < n4){
    f4v v = ((const f4v*)in)[i];
    s4v o; o[0]=f2bf(v[0]); o[1]=f2bf(v[1]); o[2]=f2bf(v[2]); o[3]=f2bf(v[3]);
    ((s4v*)out)[i] = o;
  }
}

// ---------------- 1024x1024 fp32 -> bf16 transpose (for W^T) ----------------
__global__ __launch_bounds__(256) void transpose_w_k(const float* __restrict__ in, short* __restrict__ out){
  __shared__ float t[64][65];
  int c0 = blockIdx.x*64, r0 = blockIdx.y*64;
  int tx = threadIdx.x & 63, ty = threadIdx.x >> 6;
  #pragma unroll
  for (int i=0;i<16;i++){ int r = ty + i*4; t[r][tx] = in[(size_t)(r0+r)*1024 + c0+tx]; }
  __syncthreads();
  #pragma unroll
  for (int i=0;i<16;i++){ int cc = ty + i*4; out[(size_t)(c0+cc)*1024 + r0+tx] = f2bf(t[tx][cc]); }
}

// ---------------- bf16 MFMA GEMM: C[2048][1024] f32 = A[2048][1024] @ Bt[1024][1024]^T + bias ----------------
__global__ __launch_bounds__(256) void gemm_bf16_k(const short* __restrict__ A, const short* __restrict__ Bt,
                                                   const float* __restrict__ bias, float* __restrict__ C){
  const int K = 1024, N = 1024;
  __shared__ short As[64][72];
  __shared__ short Bs[64][72];
  int m0 = blockIdx.y*64, n0 = blockIdx.x*64;
  int lane = threadIdx.x & 63, wave = threadIdx.x >> 6;
  int wr = wave >> 1, wc = wave & 1;
  int g = lane >> 4, c = lane & 15;
  f4v acc[2][2] = {};
  int trow = threadIdx.x >> 3, tcol = (threadIdx.x & 7)*8;
  for (int k0 = 0; k0 < K; k0 += 64){
    #pragma unroll
    for (int p=0;p<2;p++){
      int r = trow + p*32;
      *(s8v*)(&As[r][tcol]) = *(const s8v*)(A + (size_t)(m0+r)*K + k0 + tcol);
      *(s8v*)(&Bs[r][tcol]) = *(const s8v*)(Bt + (size_t)(n0+r)*K + k0 + tcol);
    }
    __syncthreads();
    #pragma unroll
    for (int ks=0;ks<2;ks++){
      s8v a0 = *(const s8v*)(&As[wr*32 + c][ks*32 + g*8]);
      s8v a1 = *(const s8v*)(&As[wr*32 + 16 + c][ks*32 + g*8]);
      s8v b0 = *(const s8v*)(&Bs[wc*32 + c][ks*32 + g*8]);
      s8v b1 = *(const s8v*)(&Bs[wc*32 + 16 + c][ks*32 + g*8]);
      acc[0][0] = __builtin_amdgcn_mfma_f32_16x16x32_bf16(a0,b0,acc[0][0],0,0,0);
      acc[0][1] = __builtin_amdgcn_mfma_f32_16x16x32_bf16(a0,b1,acc[0][1],0,0,0);
      acc[1][0] = __builtin_amdgcn_mfma_f32_16x16x32_bf16(a1,b0,acc[1][0],0,0,0);
      acc[1][1] = __builtin_amdgcn_mfma_f32_16x16x32_bf16(a1,b1,acc[1][1],0,0,0);
    }
    __syncthreads();
  }
  #pragma unroll
  for (int rf=0;rf<2;rf++)
    #pragma unroll
    for (int cf=0;cf<2;cf++)
      #pragma unroll
      for (int i=0;i<4;i++){
        int row = m0 + wr*32 + rf*16 + g*4 + i;
        int col = n0 + wc*32 + cf*16 + c;
        C[(size_t)row*N + col] = acc[rf][cf][i] + bias[col];
      }
}

// ---------------- RoPE + scale + head-major bf16 layout ----------------
__global__ __launch_bounds__(256) void rope_qk_k(const float* __restrict__ Q, const float* __restrict__ Kf,
                                                 const float* __restrict__ cs, const float* __restrict__ sn,
                                                 short* __restrict__ Qb, short* __restrict__ Kb){
  int idx = blockIdx.x*256 + threadIdx.x;      // over B*S*H*32 = 1M pairs
  int i = idx & 31, h = (idx>>5) & 15, s = (idx>>9) & 1023, b = idx >> 19;
  float co = cs[s*32+i], si = sn[s*32+i];
  size_t src = ((size_t)(b*1024+s))*1024 + h*64 + 2*i;
  size_t dst = ((size_t)((b*16+h)*1024 + s))*64 + 2*i;
  float qe = Q[src], qo = Q[src+1];
  const float scl = 0.125f;
  Qb[dst]   = f2bf((qe*co - qo*si)*scl);
  Qb[dst+1] = f2bf((qe*si + qo*co)*scl);
  float ke = Kf[src], ko = Kf[src+1];
  Kb[dst]   = f2bf(ke*co - ko*si);
  Kb[dst+1] = f2bf(ke*si + ko*co);
}

// ---------------- V -> V^T per head, bf16 ----------------
__global__ __launch_bounds__(256) void v_transpose_k(const float* __restrict__ V, short* __restrict__ Vt){
  __shared__ float t[64][65];
  int s0 = blockIdx.x*64; int h = blockIdx.y; int b = blockIdx.z;
  int tx = threadIdx.x & 63, ty = threadIdx.x >> 6;
  #pragma unroll
  for (int i=0;i<16;i++){ int r = ty + i*4; t[r][tx] = V[((size_t)(b*1024+s0+r))*1024 + h*64 + tx]; }
  __syncthreads();
  size_t base = ((size_t)(b*16+h))*65536;
  #pragma unroll
  for (int i=0;i<16;i++){ int d = ty + i*4; Vt[base + (size_t)d*1024 + s0 + tx] = f2bf(t[tx][d]); }
}

// ---------------- fused: scores + rel bias + entmax1.5 (Newton) + PV + rel-ctx ----------------
#define SPAD 1028
__global__ __launch_bounds__(256) void attn_fused_k(const short* __restrict__ Qb, const short* __restrict__ Kb,
                                                    const short* __restrict__ relb, const short* __restrict__ Vt,
                                                    short* __restrict__ ctxb){
  __shared__ float sc[8*SPAD];       // 32896 B; after entmax, aliased as attn bf16 [16][SPAD]
  __shared__ float pb[8][65];        // 2080 B
  __shared__ float wrow[8][72];      // 2304 B (stride 72 for f4v-aligned reads)
  __shared__ short rl_t[64][72];     // 9216 B: rel^T as bf16, rl_t[d][j]
  short* attn_l = (short*)sc;

  int lane = threadIdx.x & 63, wave = threadIdx.x >> 6;
  int g = lane >> 4, c = lane & 15;
  int bh = blockIdx.y, q0 = blockIdx.x*8;
  const short* Qh = Qb + (size_t)bh*65536;
  const short* Kh = Kb + (size_t)bh*65536;
  const short* Vh = Vt + (size_t)bh*65536;

  for (int e = threadIdx.x; e < 8*72; e += 256) ((float*)wrow)[e] = 0.f;
  for (int e = threadIdx.x; e < 65*64; e += 256){
    int j = e >> 6, d = e & 63;
    rl_t[d][j] = relb[e];
  }

  // Q fragments rows q0..q0+7 (c>=8 clamped duplicate, outputs unused)
  int qr = q0 + c; if (qr > 1023) qr = 1023;
  s8v qa0 = *(const s8v*)(Qh + qr*64 + g*8);
  s8v qa1 = *(const s8v*)(Qh + qr*64 + 32 + g*8);

  // pb[r][j] = q_row(r) . rel_emb[j] via MFMA
  {
    int ntile = (wave==3) ? 2 : 1;
    for (int t=0; t<ntile; t++){
      int jt = (t==0) ? wave : 4;
      int j = jt*16 + c;
      s8v rb0 = {}, rb1 = {};
      if (j < 65){
        rb0 = *(const s8v*)(relb + j*64 + g*8);
        rb1 = *(const s8v*)(relb + j*64 + 32 + g*8);
      }
      f4v pa = {};
      pa = __builtin_amdgcn_mfma_f32_16x16x32_bf16(qa0, rb0, pa, 0,0,0);
      pa = __builtin_amdgcn_mfma_f32_16x16x32_bf16(qa1, rb1, pa, 0,0,0);
      if (j < 65 && g < 2){
        #pragma unroll
        for (int i=0;i<4;i++) pb[g*4+i][j] = pa[i];
      }
    }
  }

  // scores: wave covers cols [wave*256, +256), rows 0..7 kept
  int kc0 = wave*256;
  for (int ct=0; ct<16; ct++){
    const short* kp = Kh + (kc0 + ct*16 + c)*64 + g*8;
    s8v b0 = *(const s8v*)(kp);
    s8v b1 = *(const s8v*)(kp + 32);
    f4v a0 = {};
    a0 = __builtin_amdgcn_mfma_f32_16x16x32_bf16(qa0, b0, a0, 0,0,0);
    a0 = __builtin_amdgcn_mfma_f32_16x16x32_bf16(qa1, b1, a0, 0,0,0);
    if (g < 2){
      int col = kc0 + ct*16 + c;
      #pragma unroll
      for (int i=0;i<4;i++) sc[(g*4+i)*SPAD + col] = a0[i];
    }
  }
  __syncthreads();

  // x-setup: wave owns rows wave*2, wave*2+1
  float x[2][16], mx[2], tau[2];
  #pragma unroll
  for (int j=0;j<2;j++){
    int r = wave*2+j; int qg = q0+r;
    mx[j] = -1e30f;
    #pragma unroll
    for (int i=0;i<16;i++){
      int col = lane + i*64;
      int dlt = col - qg; int jj = min(max(dlt,-32),32)+32;
      float v = sc[r*SPAD+col] + pb[r][jj];
      x[j][i] = v; mx[j] = fmaxf(mx[j], v);
    }
  }
  #pragma unroll
  for (int o=32;o>0;o>>=1)
    #pragma unroll
    for (int j=0;j<2;j++) mx[j] = fmaxf(mx[j], __shfl_xor(mx[j],o,64));
  #pragma unroll
  for (int j=0;j<2;j++){
    #pragma unroll
    for (int i=0;i<16;i++) x[j][i] = (x[j][i]-mx[j])*0.5f;
    tau[j] = -1.0f;
  }
  __syncthreads();   // all sc reads done; sc region may now be reused as attn_l

  // Newton on g(tau)=sum((x-tau)_+^2)-1 (convex decreasing, monotone from below)
  for (int it=0; it<7; it++){
    float S1[2], S2[2];
    #pragma unroll
    for (int j=0;j<2;j++){
      float s1=0.f, s2=0.f;
      #pragma unroll
      for (int i=0;i<16;i++){ float t = fmaxf(x[j][i]-tau[j], 0.f); s1 += t; s2 += t*t; }
      S1[j]=s1; S2[j]=s2;
    }
    #pragma unroll
    for (int o=32;o>0;o>>=1)
      #pragma unroll
      for (int j=0;j<2;j++){ S1[j]+=__shfl_xor(S1[j],o,64); S2[j]+=__shfl_xor(S2[j],o,64); }
    #pragma unroll
    for (int j=0;j<2;j++) tau[j] += (S2[j]-1.0f)/(2.0f*S1[j]);
  }

  // attn epilogue: write attn bf16 into aliased LDS + bucket weights
  float w0[2], w64v[2];
  #pragma unroll
  for (int j=0;j<2;j++){
    int r = wave*2+j; int qg = q0+r;
    float a0s=0.f, a64=0.f;
    #pragma unroll
    for (int i=0;i<16;i++){
      int col = lane + i*64;
      float t = fmaxf(x[j][i]-tau[j], 0.f); float a = t*t;
      attn_l[r*SPAD + col] = f2bf(a);
      int raw = col - qg;
      if (raw <= -32) a0s += a;
      else if (raw >= 32) a64 += a;
      else wrow[r][raw+32] = a;   // unique (row,col) owner
    }
    w0[j]=a0s; w64v[j]=a64;
  }
  #pragma unroll
  for (int o=32;o>0;o>>=1)
    #pragma unroll
    for (int j=0;j<2;j++){ w0[j]+=__shfl_xor(w0[j],o,64); w64v[j]+=__shfl_xor(w64v[j],o,64); }
  if (lane==0){
    #pragma unroll
    for (int j=0;j<2;j++){ int r=wave*2+j; wrow[r][0]=w0[j]; wrow[r][64]=w64v[j]; }
  }
  __syncthreads();

  // PV: wave owns d-cols [wave*16, +16), full K; A = attn rows (c<8), B = Vt rows d
  f4v acc = {};
  for (int kk=0; kk<32; kk++){
    s8v af = {};
    if (c < 8) af = *(const s8v*)(attn_l + c*SPAD + kk*32 + g*8);
    s8v bf = *(const s8v*)(Vh + (size_t)(wave*16+c)*1024 + kk*32 + g*8);
    acc = __builtin_amdgcn_mfma_f32_16x16x32_bf16(af, bf, acc, 0,0,0);
  }

  // ctx epilogue: rows g*4+i (g<2), d = wave*16+c; add rank-65 rel-ctx
  int b = bh >> 4, h = bh & 15, d = wave*16 + c;
  if (g < 2){
    #pragma unroll
    for (int i=0;i<4;i++){
      int r = g*4+i;
      float s = acc[i];
      #pragma unroll
      for (int jc=0; jc<8; jc++){
        s8v rv = *(const s8v*)(&rl_t[d][jc*8]);
        f4v wa = *(const f4v*)(&wrow[r][jc*8]);
        f4v wbv = *(const f4v*)(&wrow[r][jc*8+4]);
        s += wa[0]*bf2f(rv[0]) + wa[1]*bf2f(rv[1]) + wa[2]*bf2f(rv[2]) + wa[3]*bf2f(rv[3]);
        s += wbv[0]*bf2f(rv[4]) + wbv[1]*bf2f(rv[5]) + wbv[2]*bf2f(rv[6]) + wbv[3]*bf2f(rv[7]);
      }
      s += wrow[r][64]*bf2f(rl_t[d][64]);
      ctxb[((size_t)(b*1024 + q0 + r))*1024 + h*64 + d] = f2bf(s);
    }
  }
}

extern "C" void kernel_launch(void* const* d_in, const int* in_sizes, int n_in,
                              void* d_out, int out_size, void* d_ws, size_t ws_size,
                              hipStream_t stream) {
  (void)in_sizes; (void)n_in; (void)out_size; (void)ws_size;
  const float* x    = (const float*)d_in[0];
  const float* w_q  = (const float*)d_in[1];
  const float* b_q  = (const float*)d_in[2];
  const float* w_k  = (const float*)d_in[3];
  const float* b_k  = (const float*)d_in[4];
  const float* w_v  = (const float*)d_in[5];
  const float* b_v  = (const float*)d_in[6];
  const float* w_o  = (const float*)d_in[7];
  const float* b_o  = (const float*)d_in[8];
  const float* rel  = (const float*)d_in[9];
  const float* rcos = (const float*)d_in[10];
  const float* rsin = (const float*)d_in[11];
  float* out = (float*)d_out;

  char* w = (char*)d_ws;
  short* xb    = (short*)(w);                        // 4 MiB
  short* wqT   = (short*)(w + ((size_t)4<<20));      // 2 MiB each
  short* wkT   = (short*)(w + ((size_t)6<<20));
  short* wvT   = (short*)(w + ((size_t)8<<20));
  short* woT   = (short*)(w + ((size_t)10<<20));
  float* Qf    = (float*)(w + ((size_t)12<<20));     // 8 MiB each
  float* Kf    = (float*)(w + ((size_t)20<<20));
  float* Vf    = (float*)(w + ((size_t)28<<20));
  short* Qb    = (short*)(w + ((size_t)36<<20));     // 4 MiB each
  short* Kb    = (short*)(w + ((size_t)40<<20));
  short* Vt    = (short*)(w + ((size_t)44<<20));
  short* ctxb  = (short*)(w + ((size_t)48<<20));     // 4 MiB
  short* relb  = (short*)(w + ((size_t)61<<20));     // 8.3 KB

  cvt_bf16_k<<<2048, 256, 0, stream>>>(x, xb, 524288);
  cvt_bf16_k<<<5, 256, 0, stream>>>(rel, relb, 1040);
  transpose_w_k<<<dim3(16,16), 256, 0, stream>>>(w_q, wqT);
  transpose_w_k<<<dim3(16,16), 256, 0, stream>>>(w_k, wkT);
  transpose_w_k<<<dim3(16,16), 256, 0, stream>>>(w_v, wvT);
  transpose_w_k<<<dim3(16,16), 256, 0, stream>>>(w_o, woT);
  gemm_bf16_k<<<dim3(16,32), 256, 0, stream>>>(xb, wqT, b_q, Qf);
  gemm_bf16_k<<<dim3(16,32), 256, 0, stream>>>(xb, wkT, b_k, Kf);
  gemm_bf16_k<<<dim3(16,32), 256, 0, stream>>>(xb, wvT, b_v, Vf);
  rope_qk_k<<<4096, 256, 0, stream>>>(Qf, Kf, rcos, rsin, Qb, Kb);
  v_transpose_k<<<dim3(16,16,2), 256, 0, stream>>>(Vf, Vt);
  attn_fused_k<<<dim3(128,32), 256, 0, stream>>>(Qb, Kb, relb, Vt, ctxb);
  gemm_bf16_k<<<dim3(16,32), 256, 0, stream>>>(ctxb, woT, b_o, out);
}

// Round 4
// 227.154 us; speedup vs baseline: 2.4535x; 1.2981x over previous
//
#include <hip/hip_runtime.h>

typedef __attribute__((ext_vector_type(8))) short s8v;
typedef __attribute__((ext_vector_type(4))) short s4v;
typedef __attribute__((ext_vector_type(4))) float f4v;

__device__ __forceinline__ short f2bf(float f){
  union { float f; unsigned u; } v; v.f = f;
  unsigned r = v.u + 0x7fffu + ((v.u >> 16) & 1u);
  return (short)(r >> 16);
}
__device__ __forceinline__ float bf2f(short s){
  union { unsigned u; float f; } v; v.u = ((unsigned)(unsigned short)s) << 16; return v.f;
}

// ---------------- elementwise fp32 -> bf16 ----------------
__global__ __launch_bounds__(256) void cvt_bf16_k(const float* __restrict__ in, short* __restrict__ out, int n4){
  int i = blockIdx.x*256 + threadIdx.x;
  if (i < n4){
    f4v v = ((const f4v*)in)[i];
    s4v o; o[0]=f2bf(v[0]); o[1]=f2bf(v[1]); o[2]=f2bf(v[2]); o[3]=f2bf(v[3]);
    ((s4v*)out)[i] = o;
  }
}

// ---------------- 1024x1024 fp32 -> bf16 transpose (for W^T) ----------------
__global__ __launch_bounds__(256) void transpose_w_k(const float* __restrict__ in, short* __restrict__ out){
  __shared__ float t[64][65];
  int c0 = blockIdx.x*64, r0 = blockIdx.y*64;
  int tx = threadIdx.x & 63, ty = threadIdx.x >> 6;
  #pragma unroll
  for (int i=0;i<16;i++){ int r = ty + i*4; t[r][tx] = in[(size_t)(r0+r)*1024 + c0+tx]; }
  __syncthreads();
  #pragma unroll
  for (int i=0;i<16;i++){ int cc = ty + i*4; out[(size_t)(c0+cc)*1024 + r0+tx] = f2bf(t[tx][cc]); }
}

// ---------------- bf16 MFMA GEMM: C[2048][1024] f32 = A[2048][1024] @ Bt[1024][1024]^T + bias ----------------
__global__ __launch_bounds__(256) void gemm_bf16_k(const short* __restrict__ A, const short* __restrict__ Bt,
                                                   const float* __restrict__ bias, float* __restrict__ C){
  const int K = 1024, N = 1024;
  __shared__ short As[64][72];
  __shared__ short Bs[64][72];
  int m0 = blockIdx.y*64, n0 = blockIdx.x*64;
  int lane = threadIdx.x & 63, wave = threadIdx.x >> 6;
  int wr = wave >> 1, wc = wave & 1;
  int g = lane >> 4, c = lane & 15;
  f4v acc[2][2] = {};
  int trow = threadIdx.x >> 3, tcol = (threadIdx.x & 7)*8;
  for (int k0 = 0; k0 < K; k0 += 64){
    #pragma unroll
    for (int p=0;p<2;p++){
      int r = trow + p*32;
      *(s8v*)(&As[r][tcol]) = *(const s8v*)(A + (size_t)(m0+r)*K + k0 + tcol);
      *(s8v*)(&Bs[r][tcol]) = *(const s8v*)(Bt + (size_t)(n0+r)*K + k0 + tcol);
    }
    __syncthreads();
    #pragma unroll
    for (int ks=0;ks<2;ks++){
      s8v a0 = *(const s8v*)(&As[wr*32 + c][ks*32 + g*8]);
      s8v a1 = *(const s8v*)(&As[wr*32 + 16 + c][ks*32 + g*8]);
      s8v b0 = *(const s8v*)(&Bs[wc*32 + c][ks*32 + g*8]);
      s8v b1 = *(const s8v*)(&Bs[wc*32 + 16 + c][ks*32 + g*8]);
      acc[0][0] = __builtin_amdgcn_mfma_f32_16x16x32_bf16(a0,b0,acc[0][0],0,0,0);
      acc[0][1] = __builtin_amdgcn_mfma_f32_16x16x32_bf16(a0,b1,acc[0][1],0,0,0);
      acc[1][0] = __builtin_amdgcn_mfma_f32_16x16x32_bf16(a1,b0,acc[1][0],0,0,0);
      acc[1][1] = __builtin_amdgcn_mfma_f32_16x16x32_bf16(a1,b1,acc[1][1],0,0,0);
    }
    __syncthreads();
  }
  #pragma unroll
  for (int rf=0;rf<2;rf++)
    #pragma unroll
    for (int cf=0;cf<2;cf++)
      #pragma unroll
      for (int i=0;i<4;i++){
        int row = m0 + wr*32 + rf*16 + g*4 + i;
        int col = n0 + wc*32 + cf*16 + c;
        C[(size_t)row*N + col] = acc[rf][cf][i] + bias[col];
      }
}

// ---------------- RoPE + scale + head-major bf16 layout ----------------
__global__ __launch_bounds__(256) void rope_qk_k(const float* __restrict__ Q, const float* __restrict__ Kf,
                                                 const float* __restrict__ cs, const float* __restrict__ sn,
                                                 short* __restrict__ Qb, short* __restrict__ Kb){
  int idx = blockIdx.x*256 + threadIdx.x;      // over B*S*H*32 = 1M pairs
  int i = idx & 31, h = (idx>>5) & 15, s = (idx>>9) & 1023, b = idx >> 19;
  float co = cs[s*32+i], si = sn[s*32+i];
  size_t src = ((size_t)(b*1024+s))*1024 + h*64 + 2*i;
  size_t dst = ((size_t)((b*16+h)*1024 + s))*64 + 2*i;
  float qe = Q[src], qo = Q[src+1];
  const float scl = 0.125f;
  Qb[dst]   = f2bf((qe*co - qo*si)*scl);
  Qb[dst+1] = f2bf((qe*si + qo*co)*scl);
  float ke = Kf[src], ko = Kf[src+1];
  Kb[dst]   = f2bf(ke*co - ko*si);
  Kb[dst+1] = f2bf(ke*si + ko*co);
}

// ---------------- V -> V^T per head, bf16 ----------------
__global__ __launch_bounds__(256) void v_transpose_k(const float* __restrict__ V, short* __restrict__ Vt){
  __shared__ float t[64][65];
  int s0 = blockIdx.x*64; int h = blockIdx.y; int b = blockIdx.z;
  int tx = threadIdx.x & 63, ty = threadIdx.x >> 6;
  #pragma unroll
  for (int i=0;i<16;i++){ int r = ty + i*4; t[r][tx] = V[((size_t)(b*1024+s0+r))*1024 + h*64 + tx]; }
  __syncthreads();
  size_t base = ((size_t)(b*16+h))*65536;
  #pragma unroll
  for (int i=0;i<16;i++){ int d = ty + i*4; Vt[base + (size_t)d*1024 + s0 + tx] = f2bf(t[tx][d]); }
}

// ---- fused: S^T scores (reg-resident) + rel bias + entmax1.5 Newton + PV + rel-ctx MFMA ----
#define ATPAD 1032
__global__ __launch_bounds__(256) void attn_fused_k(const short* __restrict__ Qb, const short* __restrict__ Kb,
                                                    const short* __restrict__ relb, const short* __restrict__ Vt,
                                                    short* __restrict__ ctxb){
  __shared__ short rl_t[64][72];      // rel^T bf16: rl_t[d][j]
  __shared__ short pb_b[16][72];      // q.rel^T bf16: pb_b[r][j]
  __shared__ float wrow[16][66];      // bucket weights f32
  __shared__ short wrowb[16][72];     // bucket weights bf16 (j=0..63 used by MFMA)
  __shared__ short attn_l[16][ATPAD]; // attn row-major bf16
  __shared__ float2 red[2][4][16];    // cross-wave reduce, ping-pong

  int lane = threadIdx.x & 63, wave = threadIdx.x >> 6;
  int g = lane >> 4, c = lane & 15;
  int bh = blockIdx.y, q0 = blockIdx.x*16;
  const short* Qh = Qb + (size_t)bh*65536;
  const short* Kh = Kb + (size_t)bh*65536;
  const short* Vh = Vt + (size_t)bh*65536;

  for (int e = threadIdx.x; e < 16*66; e += 256) ((float*)wrow)[e] = 0.f;
  for (int e = threadIdx.x; e < 65*64; e += 256){
    int j = e >> 6, d = e & 63;
    rl_t[d][j] = relb[e];
  }

  // Q fragment (16 rows q0..q0+15)
  s8v qa0 = *(const s8v*)(Qh + (q0+c)*64 + g*8);
  s8v qa1 = *(const s8v*)(Qh + (q0+c)*64 + 32 + g*8);

  // pb[r][j] = q_row(r) . rel_emb[j] via MFMA (waves 0-3 tiles 0-3, wave3 also tile 4)
  {
    int ntile = (wave==3) ? 2 : 1;
    for (int t=0; t<ntile; t++){
      int jt = (t==0) ? wave : 4;
      int j = jt*16 + c;
      s8v rb0 = {}, rb1 = {};
      if (j < 65){
        rb0 = *(const s8v*)(relb + j*64 + g*8);
        rb1 = *(const s8v*)(relb + j*64 + 32 + g*8);
      }
      f4v pa = {};
      pa = __builtin_amdgcn_mfma_f32_16x16x32_bf16(qa0, rb0, pa, 0,0,0);
      pa = __builtin_amdgcn_mfma_f32_16x16x32_bf16(qa1, rb1, pa, 0,0,0);
      if (j < 65){
        #pragma unroll
        for (int i=0;i<4;i++) pb_b[g*4+i][j] = f2bf(pa[i]);
      }
    }
  }
  __syncthreads();

  // scores^T: lane (g,c) holds S[q0+c][k], k = kc0 + t*16 + g*4 + i; pb as C-init
  int q = q0 + c;
  int kc0 = wave*256;
  f4v x[16];
  #pragma unroll
  for (int t=0;t<16;t++){
    f4v ini;
    #pragma unroll
    for (int i=0;i<4;i++){
      int k = kc0 + t*16 + g*4 + i;
      int jj = min(max(k - q, -32), 32) + 32;
      ini[i] = bf2f(pb_b[c][jj]);
    }
    const short* kp = Kh + (kc0 + t*16 + c)*64 + g*8;
    s8v ka0 = *(const s8v*)(kp);
    s8v ka1 = *(const s8v*)(kp + 32);
    ini = __builtin_amdgcn_mfma_f32_16x16x32_bf16(ka0, qa0, ini, 0,0,0);
    x[t] = __builtin_amdgcn_mfma_f32_16x16x32_bf16(ka1, qa1, ini, 0,0,0);
  }

  // row max: in-lane (4-way ILP) + xor16/32 + cross-wave
  float m0v = -1e30f, m1v = -1e30f, m2v = -1e30f, m3v = -1e30f;
  #pragma unroll
  for (int t=0;t<16;t++){
    m0v = fmaxf(m0v, x[t][0]); m1v = fmaxf(m1v, x[t][1]);
    m2v = fmaxf(m2v, x[t][2]); m3v = fmaxf(m3v, x[t][3]);
  }
  float mx = fmaxf(fmaxf(m0v,m1v), fmaxf(m2v,m3v));
  mx = fmaxf(mx, __shfl_xor(mx, 16, 64));
  mx = fmaxf(mx, __shfl_xor(mx, 32, 64));
  if (g == 0) red[0][wave][c] = make_float2(mx, 0.f);
  __syncthreads();
  {
    float2 r0 = red[0][0][c], r1 = red[0][1][c], r2 = red[0][2][c], r3 = red[0][3][c];
    mx = fmaxf(fmaxf(r0.x, r1.x), fmaxf(r2.x, r3.x));
  }
  #pragma unroll
  for (int t=0;t<16;t++){
    x[t][0] = (x[t][0]-mx)*0.5f; x[t][1] = (x[t][1]-mx)*0.5f;
    x[t][2] = (x[t][2]-mx)*0.5f; x[t][3] = (x[t][3]-mx)*0.5f;
  }

  // Newton on g(tau)=sum((x-tau)_+^2)-1, monotone from tau0=-1
  float tau = -1.0f;
  for (int it=0; it<7; it++){
    float s1a=0.f,s1b=0.f,s1c=0.f,s1d=0.f, s2a=0.f,s2b=0.f,s2c=0.f,s2d=0.f;
    #pragma unroll
    for (int t=0;t<16;t++){
      float t0 = fmaxf(x[t][0]-tau, 0.f); s1a += t0; s2a = fmaf(t0,t0,s2a);
      float t1 = fmaxf(x[t][1]-tau, 0.f); s1b += t1; s2b = fmaf(t1,t1,s2b);
      float t2 = fmaxf(x[t][2]-tau, 0.f); s1c += t2; s2c = fmaf(t2,t2,s2c);
      float t3 = fmaxf(x[t][3]-tau, 0.f); s1d += t3; s2d = fmaf(t3,t3,s2d);
    }
    float S1 = (s1a+s1b)+(s1c+s1d), S2 = (s2a+s2b)+(s2c+s2d);
    S1 += __shfl_xor(S1, 16, 64); S2 += __shfl_xor(S2, 16, 64);
    S1 += __shfl_xor(S1, 32, 64); S2 += __shfl_xor(S2, 32, 64);
    int pp = (it+1)&1;
    if (g == 0) red[pp][wave][c] = make_float2(S1, S2);
    __syncthreads();
    float2 r0 = red[pp][0][c], r1 = red[pp][1][c], r2 = red[pp][2][c], r3 = red[pp][3][c];
    S1 = (r0.x+r1.x)+(r2.x+r3.x);
    S2 = (r0.y+r1.y)+(r2.y+r3.y);
    tau += (S2 - 1.0f)/(2.0f*S1);
  }

  // epilogue: attn bf16 -> LDS (packed b64), bucket weights
  float w0p = 0.f, w64p = 0.f;
  #pragma unroll
  for (int t=0;t<16;t++){
    s4v pk;
    #pragma unroll
    for (int i=0;i<4;i++){
      int k = kc0 + t*16 + g*4 + i;
      float tt = fmaxf(x[t][i]-tau, 0.f);
      float a = tt*tt;
      pk[i] = f2bf(a);
      int raw = k - q;
      if (raw <= -32) w0p += a;
      else if (raw >= 32) w64p += a;
      else wrow[c][raw+32] = a;   // unique (q,k) owner
    }
    *(s4v*)(&attn_l[c][kc0 + t*16 + g*4]) = pk;
  }
  w0p += __shfl_xor(w0p, 16, 64); w64p += __shfl_xor(w64p, 16, 64);
  w0p += __shfl_xor(w0p, 32, 64); w64p += __shfl_xor(w64p, 32, 64);
  if (g == 0) red[0][wave][c] = make_float2(w0p, w64p);
  __syncthreads();
  if (wave == 0 && g == 0){
    float2 r0 = red[0][0][c], r1 = red[0][1][c], r2 = red[0][2][c], r3 = red[0][3][c];
    wrow[c][0]  = (r0.x+r1.x)+(r2.x+r3.x);
    wrow[c][64] = (r0.y+r1.y)+(r2.y+r3.y);
  }
  __syncthreads();
  for (int e = threadIdx.x; e < 1024; e += 256){
    int r = e >> 6, j = e & 63;
    wrowb[r][j] = f2bf(wrow[r][j]);
  }
  __syncthreads();

  // PV: wave owns d-cols [wave*16,+16), full K=1024; + rel-ctx via 2 MFMAs
  f4v acc = {};
  #pragma unroll 8
  for (int kk=0; kk<32; kk++){
    s8v af = *(const s8v*)(&attn_l[c][kk*32 + g*8]);
    s8v bf = *(const s8v*)(Vh + (size_t)(wave*16+c)*1024 + kk*32 + g*8);
    acc = __builtin_amdgcn_mfma_f32_16x16x32_bf16(af, bf, acc, 0,0,0);
  }
  {
    s8v wa0 = *(const s8v*)(&wrowb[c][g*8]);
    s8v wa1 = *(const s8v*)(&wrowb[c][32 + g*8]);
    s8v rb0 = *(const s8v*)(&rl_t[wave*16+c][g*8]);
    s8v rb1 = *(const s8v*)(&rl_t[wave*16+c][32 + g*8]);
    acc = __builtin_amdgcn_mfma_f32_16x16x32_bf16(wa0, rb0, acc, 0,0,0);
    acc = __builtin_amdgcn_mfma_f32_16x16x32_bf16(wa1, rb1, acc, 0,0,0);
  }
  int b = bh >> 4, h = bh & 15, d = wave*16 + c;
  float rl64 = bf2f(rl_t[d][64]);
  #pragma unroll
  for (int i=0;i<4;i++){
    int r = g*4+i;
    float s = acc[i] + wrow[r][64]*rl64;
    ctxb[((size_t)(b*1024 + q0 + r))*1024 + h*64 + d] = f2bf(s);
  }
}

extern "C" void kernel_launch(void* const* d_in, const int* in_sizes, int n_in,
                              void* d_out, int out_size, void* d_ws, size_t ws_size,
                              hipStream_t stream) {
  (void)in_sizes; (void)n_in; (void)out_size; (void)ws_size;
  const float* x    = (const float*)d_in[0];
  const float* w_q  = (const float*)d_in[1];
  const float* b_q  = (const float*)d_in[2];
  const float* w_k  = (const float*)d_in[3];
  const float* b_k  = (const float*)d_in[4];
  const float* w_v  = (const float*)d_in[5];
  const float* b_v  = (const float*)d_in[6];
  const float* w_o  = (const float*)d_in[7];
  const float* b_o  = (const float*)d_in[8];
  const float* rel  = (const float*)d_in[9];
  const float* rcos = (const float*)d_in[10];
  const float* rsin = (const float*)d_in[11];
  float* out = (float*)d_out;

  char* w = (char*)d_ws;
  short* xb    = (short*)(w);                        // 4 MiB
  short* wqT   = (short*)(w + ((size_t)4<<20));      // 2 MiB each
  short* wkT   = (short*)(w + ((size_t)6<<20));
  short* wvT   = (short*)(w + ((size_t)8<<20));
  short* woT   = (short*)(w + ((size_t)10<<20));
  float* Qf    = (float*)(w + ((size_t)12<<20));     // 8 MiB each
  float* Kf    = (float*)(w + ((size_t)20<<20));
  float* Vf    = (float*)(w + ((size_t)28<<20));
  short* Qb    = (short*)(w + ((size_t)36<<20));     // 4 MiB each
  short* Kb    = (short*)(w + ((size_t)40<<20));
  short* Vt    = (short*)(w + ((size_t)44<<20));
  short* ctxb  = (short*)(w + ((size_t)48<<20));     // 4 MiB
  short* relb  = (short*)(w + ((size_t)61<<20));     // 8.3 KB

  cvt_bf16_k<<<2048, 256, 0, stream>>>(x, xb, 524288);
  cvt_bf16_k<<<5, 256, 0, stream>>>(rel, relb, 1040);
  transpose_w_k<<<dim3(16,16), 256, 0, stream>>>(w_q, wqT);
  transpose_w_k<<<dim3(16,16), 256, 0, stream>>>(w_k, wkT);
  transpose_w_k<<<dim3(16,16), 256, 0, stream>>>(w_v, wvT);
  transpose_w_k<<<dim3(16,16), 256, 0, stream>>>(w_o, woT);
  gemm_bf16_k<<<dim3(16,32), 256, 0, stream>>>(xb, wqT, b_q, Qf);
  gemm_bf16_k<<<dim3(16,32), 256, 0, stream>>>(xb, wkT, b_k, Kf);
  gemm_bf16_k<<<dim3(16,32), 256, 0, stream>>>(xb, wvT, b_v, Vf);
  rope_qk_k<<<4096, 256, 0, stream>>>(Qf, Kf, rcos, rsin, Qb, Kb);
  v_transpose_k<<<dim3(16,16,2), 256, 0, stream>>>(Vf, Vt);
  attn_fused_k<<<dim3(64,32), 256, 0, stream>>>(Qb, Kb, relb, Vt, ctxb);
  gemm_bf16_k<<<dim3(16,32), 256, 0, stream>>>(ctxb, woT, b_o, out);
}

// Round 5
// 175.591 us; speedup vs baseline: 3.1740x; 1.2937x over previous
//
#include <hip/hip_runtime.h>

typedef __attribute__((ext_vector_type(8))) short s8v;
typedef __attribute__((ext_vector_type(4))) short s4v;
typedef __attribute__((ext_vector_type(4))) float f4v;

__device__ __forceinline__ short f2bf(float f){
  union { float f; unsigned u; } v; v.f = f;
  unsigned r = v.u + 0x7fffu + ((v.u >> 16) & 1u);
  return (short)(r >> 16);
}
__device__ __forceinline__ float bf2f(short s){
  union { unsigned u; float f; } v; v.u = ((unsigned)(unsigned short)s) << 16; return v.f;
}

// ---------------- elementwise fp32 -> bf16 ----------------
__global__ __launch_bounds__(256) void cvt_bf16_k(const float* __restrict__ in, short* __restrict__ out, int n4){
  int i = blockIdx.x*256 + threadIdx.x;
  if (i < n4){
    f4v v = ((const f4v*)in)[i];
    s4v o; o[0]=f2bf(v[0]); o[1]=f2bf(v[1]); o[2]=f2bf(v[2]); o[3]=f2bf(v[3]);
    ((s4v*)out)[i] = o;
  }
}

// ---------------- rel prep: rel f32 [65][64] -> relb bf16 row-major + relT bf16 [64][72] ----------------
__global__ __launch_bounds__(256) void prep_rel_k(const float* __restrict__ rel, short* __restrict__ relb,
                                                  short* __restrict__ relT){
  for (int e = threadIdx.x; e < 65*64; e += 256){
    int j = e >> 6, d = e & 63;
    short bv = f2bf(rel[e]);
    relb[e] = bv;
    relT[d*72 + j] = bv;
  }
}

// ---------------- 1024x1024 fp32 -> bf16 transpose (for W^T) ----------------
__global__ __launch_bounds__(256) void transpose_w_k(const float* __restrict__ in, short* __restrict__ out){
  __shared__ float t[64][65];
  int c0 = blockIdx.x*64, r0 = blockIdx.y*64;
  int tx = threadIdx.x & 63, ty = threadIdx.x >> 6;
  #pragma unroll
  for (int i=0;i<16;i++){ int r = ty + i*4; t[r][tx] = in[(size_t)(r0+r)*1024 + c0+tx]; }
  __syncthreads();
  #pragma unroll
  for (int i=0;i<16;i++){ int cc = ty + i*4; out[(size_t)(c0+cc)*1024 + r0+tx] = f2bf(t[tx][cc]); }
}

// ---------------- bf16 MFMA GEMM: C[2048][1024] f32 = A @ Bt^T + bias (out-proj) ----------------
__global__ __launch_bounds__(256) void gemm_bf16_k(const short* __restrict__ A, const short* __restrict__ Bt,
                                                   const float* __restrict__ bias, float* __restrict__ C){
  const int K = 1024, N = 1024;
  __shared__ short As[64][72];
  __shared__ short Bs[64][72];
  int m0 = blockIdx.y*64, n0 = blockIdx.x*64;
  int lane = threadIdx.x & 63, wave = threadIdx.x >> 6;
  int wr = wave >> 1, wc = wave & 1;
  int g = lane >> 4, c = lane & 15;
  f4v acc[2][2] = {};
  int trow = threadIdx.x >> 3, tcol = (threadIdx.x & 7)*8;
  for (int k0 = 0; k0 < K; k0 += 64){
    #pragma unroll
    for (int p=0;p<2;p++){
      int r = trow + p*32;
      *(s8v*)(&As[r][tcol]) = *(const s8v*)(A + (size_t)(m0+r)*K + k0 + tcol);
      *(s8v*)(&Bs[r][tcol]) = *(const s8v*)(Bt + (size_t)(n0+r)*K + k0 + tcol);
    }
    __syncthreads();
    #pragma unroll
    for (int ks=0;ks<2;ks++){
      s8v a0 = *(const s8v*)(&As[wr*32 + c][ks*32 + g*8]);
      s8v a1 = *(const s8v*)(&As[wr*32 + 16 + c][ks*32 + g*8]);
      s8v b0 = *(const s8v*)(&Bs[wc*32 + c][ks*32 + g*8]);
      s8v b1 = *(const s8v*)(&Bs[wc*32 + 16 + c][ks*32 + g*8]);
      acc[0][0] = __builtin_amdgcn_mfma_f32_16x16x32_bf16(a0,b0,acc[0][0],0,0,0);
      acc[0][1] = __builtin_amdgcn_mfma_f32_16x16x32_bf16(a0,b1,acc[0][1],0,0,0);
      acc[1][0] = __builtin_amdgcn_mfma_f32_16x16x32_bf16(a1,b0,acc[1][0],0,0,0);
      acc[1][1] = __builtin_amdgcn_mfma_f32_16x16x32_bf16(a1,b1,acc[1][1],0,0,0);
    }
    __syncthreads();
  }
  #pragma unroll
  for (int rf=0;rf<2;rf++)
    #pragma unroll
    for (int cf=0;cf<2;cf++)
      #pragma unroll
      for (int i=0;i<4;i++){
        int row = m0 + wr*32 + rf*16 + g*4 + i;
        int col = n0 + wc*32 + cf*16 + c;
        C[(size_t)row*N + col] = acc[rf][cf][i] + bias[col];
      }
}

// ---------------- fused QKV GEMM: A[2048][1024] @ wqkvT[3072][1024]^T, epilogue bias+RoPE+layout ----------------
__global__ __launch_bounds__(256) void gemm_qkv_k(const short* __restrict__ A, const short* __restrict__ Bt,
                                                  const float* __restrict__ b_q, const float* __restrict__ b_k,
                                                  const float* __restrict__ b_v,
                                                  const float* __restrict__ cs, const float* __restrict__ sn,
                                                  short* __restrict__ Qb, short* __restrict__ Kb,
                                                  short* __restrict__ Vt){
  const int K = 1024;
  __shared__ short As[64][72];
  __shared__ short Bs[64][72];
  int m0 = blockIdx.y*64, n0 = blockIdx.x*64;
  int lane = threadIdx.x & 63, wave = threadIdx.x >> 6;
  int wr = wave >> 1, wc = wave & 1;
  int g = lane >> 4, c = lane & 15;
  f4v acc[2][2] = {};
  int trow = threadIdx.x >> 3, tcol = (threadIdx.x & 7)*8;
  for (int k0 = 0; k0 < K; k0 += 64){
    #pragma unroll
    for (int p=0;p<2;p++){
      int r = trow + p*32;
      *(s8v*)(&As[r][tcol]) = *(const s8v*)(A + (size_t)(m0+r)*K + k0 + tcol);
      *(s8v*)(&Bs[r][tcol]) = *(const s8v*)(Bt + (size_t)(n0+r)*K + k0 + tcol);
    }
    __syncthreads();
    #pragma unroll
    for (int ks=0;ks<2;ks++){
      s8v a0 = *(const s8v*)(&As[wr*32 + c][ks*32 + g*8]);
      s8v a1 = *(const s8v*)(&As[wr*32 + 16 + c][ks*32 + g*8]);
      s8v b0 = *(const s8v*)(&Bs[wc*32 + c][ks*32 + g*8]);
      s8v b1 = *(const s8v*)(&Bs[wc*32 + 16 + c][ks*32 + g*8]);
      acc[0][0] = __builtin_amdgcn_mfma_f32_16x16x32_bf16(a0,b0,acc[0][0],0,0,0);
      acc[0][1] = __builtin_amdgcn_mfma_f32_16x16x32_bf16(a0,b1,acc[0][1],0,0,0);
      acc[1][0] = __builtin_amdgcn_mfma_f32_16x16x32_bf16(a1,b0,acc[1][0],0,0,0);
      acc[1][1] = __builtin_amdgcn_mfma_f32_16x16x32_bf16(a1,b1,acc[1][1],0,0,0);
    }
    __syncthreads();
  }

  // epilogue: bias (+RoPE for Q/K, +0.125 scale for Q), stage bf16 tile in LDS (stride 66), write layouts
  int sec = n0 >> 10;                      // 0=Q 1=K 2=V (block-uniform)
  const float* bias = (sec==0) ? b_q : (sec==1) ? b_k : b_v;
  short* st = &As[0][0];                   // reuse As as [64][66]-strided staging
  #pragma unroll
  for (int rf=0;rf<2;rf++)
    #pragma unroll
    for (int cf=0;cf<2;cf++){
      int cl = wc*32 + cf*16 + c;          // 0..63 local col
      float bi = bias[(n0 & 1023) + cl];
      #pragma unroll
      for (int i=0;i<4;i++){
        int rl = wr*32 + rf*16 + g*4 + i;  // 0..63 local row
        float v = acc[rf][cf][i] + bi;
        if (sec < 2){
          int s = (m0 + rl) & 1023;
          int ifr = (cl & 63) >> 1;
          float co = cs[s*32 + ifr], si = sn[s*32 + ifr];
          float p = __shfl_xor(v, 1, 64);  // partner col (c^1), same rf/cf/i
          float o = (cl & 1) ? fmaf(p, si, v*co) : fmaf(v, co, -(p*si));
          if (sec == 0) o *= 0.125f;
          v = o;
        }
        st[rl*66 + cl] = f2bf(v);
      }
    }
  __syncthreads();
  int b = m0 >> 10, s0 = m0 & 1023, h = (n0 >> 6) & 15;
  int ty = threadIdx.x >> 6, tx = threadIdx.x & 63;
  if (sec < 2){
    short* dst = (sec==0) ? Qb : Kb;
    size_t base = ((size_t)(b*16+h)*1024 + s0)*64;
    #pragma unroll
    for (int p2=0;p2<16;p2++){
      int srow = p2*4 + ty;
      dst[base + srow*64 + tx] = st[srow*66 + tx];
    }
  } else {
    size_t base = (size_t)(b*16+h)*65536;
    #pragma unroll
    for (int p2=0;p2<16;p2++){
      int d = p2*4 + ty;
      Vt[base + (size_t)d*1024 + s0 + tx] = st[tx*66 + d];
    }
  }
}

// ---- fused: S^T scores (reg-resident) + rel bias + entmax1.5 Newton + PV + rel-ctx MFMA ----
#define ATPAD 1028
__global__ __launch_bounds__(256) void attn_fused_k(const short* __restrict__ Qb, const short* __restrict__ Kb,
                                                    const short* __restrict__ relb, const short* __restrict__ relT,
                                                    const short* __restrict__ Vt, short* __restrict__ ctxb){
  __shared__ __align__(16) short pb_b[16][66];       // q.rel^T bf16; later aliased as reduce scratch
  __shared__ __align__(16) float wrow[16][68];       // bucket weights f32
  __shared__ __align__(16) short attn_l[16][ATPAD];  // attn row-major bf16
  float2* red = (float2*)&pb_b[0][0];                // red[(pp*4+w)*16+c], 1024 B <= 2112 B

  int lane = threadIdx.x & 63, wave = threadIdx.x >> 6;
  int g = lane >> 4, c = lane & 15;
  int bh = blockIdx.y, q0 = blockIdx.x*16;
  const short* Qh = Qb + (size_t)bh*65536;
  const short* Kh = Kb + (size_t)bh*65536;
  const short* Vh = Vt + (size_t)bh*65536;

  for (int e = threadIdx.x; e < 16*68; e += 256) ((float*)wrow)[e] = 0.f;

  // Q fragment (16 rows q0..q0+15)
  s8v qa0 = *(const s8v*)(Qh + (q0+c)*64 + g*8);
  s8v qa1 = *(const s8v*)(Qh + (q0+c)*64 + 32 + g*8);

  // pb[r][j] = q_row(r) . rel_emb[j] via MFMA
  {
    int ntile = (wave==3) ? 2 : 1;
    for (int t=0; t<ntile; t++){
      int jt = (t==0) ? wave : 4;
      int j = jt*16 + c;
      s8v rb0 = {}, rb1 = {};
      if (j < 65){
        rb0 = *(const s8v*)(relb + j*64 + g*8);
        rb1 = *(const s8v*)(relb + j*64 + 32 + g*8);
      }
      f4v pa = {};
      pa = __builtin_amdgcn_mfma_f32_16x16x32_bf16(qa0, rb0, pa, 0,0,0);
      pa = __builtin_amdgcn_mfma_f32_16x16x32_bf16(qa1, rb1, pa, 0,0,0);
      if (j < 65){
        #pragma unroll
        for (int i=0;i<4;i++) pb_b[g*4+i][j] = f2bf(pa[i]);
      }
    }
  }
  __syncthreads();

  // scores^T: lane (g,c) holds S[q0+c][k], k = kc0 + t*16 + g*4 + i; pb as C-init
  int q = q0 + c;
  int kc0 = wave*256;
  f4v x[16];
  #pragma unroll
  for (int t=0;t<16;t++){
    f4v ini;
    #pragma unroll
    for (int i=0;i<4;i++){
      int k = kc0 + t*16 + g*4 + i;
      int jj = min(max(k - q, -32), 32) + 32;
      ini[i] = bf2f(pb_b[c][jj]);
    }
    const short* kp = Kh + (kc0 + t*16 + c)*64 + g*8;
    s8v ka0 = *(const s8v*)(kp);
    s8v ka1 = *(const s8v*)(kp + 32);
    ini = __builtin_amdgcn_mfma_f32_16x16x32_bf16(ka0, qa0, ini, 0,0,0);
    x[t] = __builtin_amdgcn_mfma_f32_16x16x32_bf16(ka1, qa1, ini, 0,0,0);
  }
  __syncthreads();   // pb_b dead from here; red alias safe

  // row max: in-lane (4-way ILP) + xor16/32 + cross-wave
  float m0v = -1e30f, m1v = -1e30f, m2v = -1e30f, m3v = -1e30f;
  #pragma unroll
  for (int t=0;t<16;t++){
    m0v = fmaxf(m0v, x[t][0]); m1v = fmaxf(m1v, x[t][1]);
    m2v = fmaxf(m2v, x[t][2]); m3v = fmaxf(m3v, x[t][3]);
  }
  float mx = fmaxf(fmaxf(m0v,m1v), fmaxf(m2v,m3v));
  mx = fmaxf(mx, __shfl_xor(mx, 16, 64));
  mx = fmaxf(mx, __shfl_xor(mx, 32, 64));
  if (g == 0) red[wave*16 + c] = make_float2(mx, 0.f);
  __syncthreads();
  {
    float2 r0 = red[c], r1 = red[16+c], r2 = red[32+c], r3 = red[48+c];
    mx = fmaxf(fmaxf(r0.x, r1.x), fmaxf(r2.x, r3.x));
  }
  #pragma unroll
  for (int t=0;t<16;t++){
    x[t][0] = (x[t][0]-mx)*0.5f; x[t][1] = (x[t][1]-mx)*0.5f;
    x[t][2] = (x[t][2]-mx)*0.5f; x[t][3] = (x[t][3]-mx)*0.5f;
  }

  // Newton on g(tau)=sum((x-tau)_+^2)-1, monotone from tau0=-1
  float tau = -1.0f;
  for (int it=0; it<7; it++){
    float s1a=0.f,s1b=0.f,s1c=0.f,s1d=0.f, s2a=0.f,s2b=0.f,s2c=0.f,s2d=0.f;
    #pragma unroll
    for (int t=0;t<16;t++){
      float t0 = fmaxf(x[t][0]-tau, 0.f); s1a += t0; s2a = fmaf(t0,t0,s2a);
      float t1 = fmaxf(x[t][1]-tau, 0.f); s1b += t1; s2b = fmaf(t1,t1,s2b);
      float t2 = fmaxf(x[t][2]-tau, 0.f); s1c += t2; s2c = fmaf(t2,t2,s2c);
      float t3 = fmaxf(x[t][3]-tau, 0.f); s1d += t3; s2d = fmaf(t3,t3,s2d);
    }
    float S1 = (s1a+s1b)+(s1c+s1d), S2 = (s2a+s2b)+(s2c+s2d);
    S1 += __shfl_xor(S1, 16, 64); S2 += __shfl_xor(S2, 16, 64);
    S1 += __shfl_xor(S1, 32, 64); S2 += __shfl_xor(S2, 32, 64);
    int pp = (it+1)&1;
    if (g == 0) red[(pp*4 + wave)*16 + c] = make_float2(S1, S2);
    __syncthreads();
    float2 r0 = red[pp*64 + c], r1 = red[pp*64 + 16+c], r2 = red[pp*64 + 32+c], r3 = red[pp*64 + 48+c];
    S1 = (r0.x+r1.x)+(r2.x+r3.x);
    S2 = (r0.y+r1.y)+(r2.y+r3.y);
    tau += (S2 - 1.0f)/(2.0f*S1);
  }

  // epilogue: attn bf16 -> LDS (packed b64), bucket weights
  float w0p = 0.f, w64p = 0.f;
  #pragma unroll
  for (int t=0;t<16;t++){
    s4v pk;
    #pragma unroll
    for (int i=0;i<4;i++){
      int k = kc0 + t*16 + g*4 + i;
      float tt = fmaxf(x[t][i]-tau, 0.f);
      float a = tt*tt;
      pk[i] = f2bf(a);
      int raw = k - q;
      if (raw <= -32) w0p += a;
      else if (raw >= 32) w64p += a;
      else wrow[c][raw+32] = a;   // unique (q,k) owner
    }
    *(s4v*)(&attn_l[c][kc0 + t*16 + g*4]) = pk;
  }
  w0p += __shfl_xor(w0p, 16, 64); w64p += __shfl_xor(w64p, 16, 64);
  w0p += __shfl_xor(w0p, 32, 64); w64p += __shfl_xor(w64p, 32, 64);
  if (g == 0) red[wave*16 + c] = make_float2(w0p, w64p);   // red[0] region; disjoint from Newton's last pp=1 reads
  __syncthreads();
  if (wave == 0 && g == 0){
    float2 r0 = red[c], r1 = red[16+c], r2 = red[32+c], r3 = red[48+c];
    wrow[c][0]  = (r0.x+r1.x)+(r2.x+r3.x);
    wrow[c][64] = (r0.y+r1.y)+(r2.y+r3.y);
  }
  __syncthreads();

  // PV: wave owns d-cols [wave*16,+16), full K=1024; + rel-ctx via 2 MFMAs (weights cvt in-reg, rel from global)
  f4v acc = {};
  #pragma unroll 8
  for (int kk=0; kk<32; kk++){
    s8v af = *(const s8v*)(&attn_l[c][kk*32 + g*8]);
    s8v bf = *(const s8v*)(Vh + (size_t)(wave*16+c)*1024 + kk*32 + g*8);
    acc = __builtin_amdgcn_mfma_f32_16x16x32_bf16(af, bf, acc, 0,0,0);
  }
  {
    const float* wp = &wrow[c][0];
    f4v a_ = *(const f4v*)(wp + g*8);
    f4v b_ = *(const f4v*)(wp + g*8 + 4);
    f4v c_ = *(const f4v*)(wp + 32 + g*8);
    f4v d_ = *(const f4v*)(wp + 32 + g*8 + 4);
    s8v wa0, wa1;
    wa0[0]=f2bf(a_[0]); wa0[1]=f2bf(a_[1]); wa0[2]=f2bf(a_[2]); wa0[3]=f2bf(a_[3]);
    wa0[4]=f2bf(b_[0]); wa0[5]=f2bf(b_[1]); wa0[6]=f2bf(b_[2]); wa0[7]=f2bf(b_[3]);
    wa1[0]=f2bf(c_[0]); wa1[1]=f2bf(c_[1]); wa1[2]=f2bf(c_[2]); wa1[3]=f2bf(c_[3]);
    wa1[4]=f2bf(d_[0]); wa1[5]=f2bf(d_[1]); wa1[6]=f2bf(d_[2]); wa1[7]=f2bf(d_[3]);
    s8v rb0 = *(const s8v*)(relT + (wave*16+c)*72 + g*8);
    s8v rb1 = *(const s8v*)(relT + (wave*16+c)*72 + 32 + g*8);
    acc = __builtin_amdgcn_mfma_f32_16x16x32_bf16(wa0, rb0, acc, 0,0,0);
    acc = __builtin_amdgcn_mfma_f32_16x16x32_bf16(wa1, rb1, acc, 0,0,0);
  }
  int b = bh >> 4, h = bh & 15, d = wave*16 + c;
  float rl64 = bf2f(relT[d*72 + 64]);
  #pragma unroll
  for (int i=0;i<4;i++){
    int r = g*4+i;
    float s = acc[i] + wrow[r][64]*rl64;
    ctxb[((size_t)(b*1024 + q0 + r))*1024 + h*64 + d] = f2bf(s);
  }
}

extern "C" void kernel_launch(void* const* d_in, const int* in_sizes, int n_in,
                              void* d_out, int out_size, void* d_ws, size_t ws_size,
                              hipStream_t stream) {
  (void)in_sizes; (void)n_in; (void)out_size; (void)ws_size;
  const float* x    = (const float*)d_in[0];
  const float* w_q  = (const float*)d_in[1];
  const float* b_q  = (const float*)d_in[2];
  const float* w_k  = (const float*)d_in[3];
  const float* b_k  = (const float*)d_in[4];
  const float* w_v  = (const float*)d_in[5];
  const float* b_v  = (const float*)d_in[6];
  const float* w_o  = (const float*)d_in[7];
  const float* b_o  = (const float*)d_in[8];
  const float* rel  = (const float*)d_in[9];
  const float* rcos = (const float*)d_in[10];
  const float* rsin = (const float*)d_in[11];
  float* out = (float*)d_out;

  char* w = (char*)d_ws;
  short* xb    = (short*)(w);                        // 4 MiB
  short* wqkvT = (short*)(w + ((size_t)4<<20));      // 6 MiB  [3072][1024]
  short* woT   = (short*)(w + ((size_t)10<<20));     // 2 MiB
  short* Qb    = (short*)(w + ((size_t)12<<20));     // 4 MiB
  short* Kb    = (short*)(w + ((size_t)16<<20));     // 4 MiB
  short* Vt    = (short*)(w + ((size_t)20<<20));     // 4 MiB
  short* ctxb  = (short*)(w + ((size_t)24<<20));     // 4 MiB
  short* relb  = (short*)(w + ((size_t)28<<20));     // 8.3 KB
  short* relT  = (short*)(w + ((size_t)28<<20) + 65536); // 9.2 KB

  cvt_bf16_k<<<2048, 256, 0, stream>>>(x, xb, 524288);
  prep_rel_k<<<1, 256, 0, stream>>>(rel, relb, relT);
  transpose_w_k<<<dim3(16,16), 256, 0, stream>>>(w_q, wqkvT);
  transpose_w_k<<<dim3(16,16), 256, 0, stream>>>(w_k, wqkvT + (1<<20));
  transpose_w_k<<<dim3(16,16), 256, 0, stream>>>(w_v, wqkvT + (2<<20));
  transpose_w_k<<<dim3(16,16), 256, 0, stream>>>(w_o, woT);
  gemm_qkv_k<<<dim3(48,32), 256, 0, stream>>>(xb, wqkvT, b_q, b_k, b_v, rcos, rsin, Qb, Kb, Vt);
  attn_fused_k<<<dim3(64,32), 256, 0, stream>>>(Qb, Kb, relb, relT, Vt, ctxb);
  gemm_bf16_k<<<dim3(16,32), 256, 0, stream>>>(ctxb, woT, b_o, out);
}

// Round 6
// 138.443 us; speedup vs baseline: 4.0257x; 1.2683x over previous
//
#include <hip/hip_runtime.h>

typedef __attribute__((ext_vector_type(8))) short s8v;
typedef __attribute__((ext_vector_type(4))) short s4v;
typedef __attribute__((ext_vector_type(4))) float f4v;

__device__ __forceinline__ short f2bf(float f){
  union { float f; unsigned u; } v; v.f = f;
  unsigned r = v.u + 0x7fffu + ((v.u >> 16) & 1u);
  return (short)(r >> 16);
}
__device__ __forceinline__ float bf2f(short s){
  union { unsigned u; float f; } v; v.u = ((unsigned)(unsigned short)s) << 16; return v.f;
}

// ---------------- unified prep: 4 W-transposes (z=0..3), x->bf16 (z=4..5), rel prep (block 0,0,3) ----------------
__global__ __launch_bounds__(256) void prep_k(const float* __restrict__ w_q, const float* __restrict__ w_k,
                                              const float* __restrict__ w_v, const float* __restrict__ w_o,
                                              const float* __restrict__ x, const float* __restrict__ rel,
                                              short* __restrict__ wqkvT, short* __restrict__ woT,
                                              short* __restrict__ xb, short* __restrict__ relb,
                                              short* __restrict__ relT){
  int z = blockIdx.z;
  if (z < 4){
    __shared__ float t[64][65];
    const float* in = (z==0) ? w_q : (z==1) ? w_k : (z==2) ? w_v : w_o;
    short* out = (z==3) ? woT : (wqkvT + ((size_t)z<<20));
    int c0 = blockIdx.x*64, r0 = blockIdx.y*64;
    int tx = threadIdx.x & 63, ty = threadIdx.x >> 6;
    #pragma unroll
    for (int i=0;i<16;i++){ int r = ty + i*4; t[r][tx] = in[(size_t)(r0+r)*1024 + c0+tx]; }
    __syncthreads();
    #pragma unroll
    for (int i=0;i<16;i++){ int cc = ty + i*4; out[(size_t)(c0+cc)*1024 + r0+tx] = f2bf(t[tx][cc]); }
    if (z==3 && blockIdx.x==0 && blockIdx.y==0){
      for (int e = threadIdx.x; e < 65*64; e += 256){
        int j = e >> 6, d = e & 63;
        short bv = f2bf(rel[e]);
        relb[e] = bv;
        relT[d*72 + j] = bv;
      }
    }
  } else {
    int bid = (z-4)*256 + blockIdx.y*16 + blockIdx.x;   // 0..511
    int i = bid*256 + threadIdx.x;                       // 0..131071
    #pragma unroll
    for (int p=0;p<4;p++){
      int idx = p*131072 + i;
      f4v v = ((const f4v*)x)[idx];
      s4v o; o[0]=f2bf(v[0]); o[1]=f2bf(v[1]); o[2]=f2bf(v[2]); o[3]=f2bf(v[3]);
      ((s4v*)xb)[idx] = o;
    }
  }
}

// ---------------- 128x128-tile bf16 MFMA GEMM core (BK=64, 4 waves, 4x4 acc, XOR unit-swizzled LDS) ----------------
__device__ __forceinline__ void gemm128_core(const short* __restrict__ A, const short* __restrict__ Bt,
                                             int m0, int n0, short* As, short* Bs, f4v acc[4][4]){
  int tid = threadIdx.x;
  int lane = tid & 63, wave = tid >> 6;
  int wr = wave >> 1, wc = wave & 1, g = lane >> 4, c = lane & 15;
  int srow = tid >> 3, su = tid & 7;
  for (int k0 = 0; k0 < 1024; k0 += 64){
    #pragma unroll
    for (int p=0;p<4;p++){
      int r = srow + p*32;
      int u = su ^ (r & 7);
      *(s8v*)(&As[r*64 + u*8]) = *(const s8v*)(A + (size_t)(m0+r)*1024 + k0 + su*8);
      *(s8v*)(&Bs[r*64 + u*8]) = *(const s8v*)(Bt + (size_t)(n0+r)*1024 + k0 + su*8);
    }
    __syncthreads();
    #pragma unroll
    for (int ks=0;ks<2;ks++){
      s8v a[4], b[4];
      int pu = ((ks*4 + g) ^ (c & 7))*8;
      #pragma unroll
      for (int mi=0;mi<4;mi++) a[mi] = *(const s8v*)(&As[(wr*64 + mi*16 + c)*64 + pu]);
      #pragma unroll
      for (int ni=0;ni<4;ni++) b[ni] = *(const s8v*)(&Bs[(wc*64 + ni*16 + c)*64 + pu]);
      #pragma unroll
      for (int mi=0;mi<4;mi++)
        #pragma unroll
        for (int ni=0;ni<4;ni++)
          acc[mi][ni] = __builtin_amdgcn_mfma_f32_16x16x32_bf16(a[mi], b[ni], acc[mi][ni], 0,0,0);
    }
    __syncthreads();
  }
}

// ---------------- fused QKV GEMM (128^2): bias + RoPE + head-major/transposed layouts ----------------
__global__ __launch_bounds__(256) void gemm_qkv_k(const short* __restrict__ A, const short* __restrict__ Bt,
                                                  const float* __restrict__ b_q, const float* __restrict__ b_k,
                                                  const float* __restrict__ b_v,
                                                  const float* __restrict__ cs, const float* __restrict__ sn,
                                                  short* __restrict__ Qb, short* __restrict__ Kb,
                                                  short* __restrict__ Vt){
  __shared__ __align__(16) char lbuf[33792];   // staging 2x16KB; epilogue st[128][132] bf16 (33792B)
  short* As = (short*)lbuf;
  short* Bs = (short*)(lbuf + 16384);
  short* st = (short*)lbuf;
  int flat = blockIdx.x;                        // 384 blocks
  int swz = (flat & 7)*48 + (flat >> 3);        // XCD-contiguous chunks
  int m0 = (swz / 24) * 128, n0 = (swz % 24) * 128;
  int lane = threadIdx.x & 63, wave = threadIdx.x >> 6;
  int wr = wave >> 1, wc = wave & 1, g = lane >> 4, c = lane & 15;
  f4v acc[4][4] = {};
  gemm128_core(A, Bt, m0, n0, As, Bs, acc);

  int sec = n0 >> 10;                           // 0=Q 1=K 2=V (uniform)
  const float* bias = (sec==0) ? b_q : (sec==1) ? b_k : b_v;
  int b = m0 >> 10, s0 = m0 & 1023, hbase = (n0 & 1023) >> 6;
  #pragma unroll
  for (int mi=0;mi<4;mi++)
    #pragma unroll
    for (int ni=0;ni<4;ni++){
      int cl = wc*64 + ni*16 + c;
      int hcol = (n0 & 1023) + cl;
      float bi = bias[hcol];
      int d = hcol & 63, ifr = d >> 1;
      #pragma unroll
      for (int i=0;i<4;i++){
        int rl = wr*64 + mi*16 + g*4 + i;
        float v = acc[mi][ni][i] + bi;
        if (sec < 2){
          int s = s0 + rl;
          float co = cs[s*32 + ifr], si = sn[s*32 + ifr];
          float p = __shfl_xor(v, 1, 64);      // partner col cl^1 (lane c^1), same row
          float o = (cl & 1) ? fmaf(p, si, v*co) : fmaf(v, co, -(p*si));
          if (sec == 0) o *= 0.125f;
          v = o;
        }
        st[rl*132 + cl] = f2bf(v);
      }
    }
  __syncthreads();
  if (sec < 2){
    short* dst = (sec==0) ? Qb : Kb;
    for (int e = threadIdx.x; e < 128*32; e += 256){
      int row = e >> 5, cl4 = (e & 31)*4;
      int h = hbase + (cl4 >> 6), d = cl4 & 63;
      s4v o = *(const s4v*)(&st[row*132 + cl4]);
      *(s4v*)(&dst[((size_t)(b*16+h)*1024 + s0 + row)*64 + d]) = o;
    }
  } else {
    for (int e = threadIdx.x; e < 128*32; e += 256){
      int cl = e >> 5, s4 = (e & 31)*4;
      int h = hbase + (cl >> 6), dl = cl & 63;
      s4v o;
      o[0] = st[(s4+0)*132 + cl]; o[1] = st[(s4+1)*132 + cl];
      o[2] = st[(s4+2)*132 + cl]; o[3] = st[(s4+3)*132 + cl];
      *(s4v*)(&Vt[(size_t)(b*16+h)*65536 + (size_t)dl*1024 + s0 + s4]) = o;
    }
  }
}

// ---------------- out-proj GEMM (128^2): C f32 = A @ woT^T + b_o ----------------
__global__ __launch_bounds__(256) void gemm_out_k(const short* __restrict__ A, const short* __restrict__ Bt,
                                                  const float* __restrict__ bias, float* __restrict__ C){
  __shared__ __align__(16) short As[128*64];
  __shared__ __align__(16) short Bs[128*64];
  int flat = blockIdx.x;                        // 128 blocks
  int swz = (flat & 7)*16 + (flat >> 3);
  int n0 = (swz & 7)*128, m0 = (swz >> 3)*128;
  int lane = threadIdx.x & 63, wave = threadIdx.x >> 6;
  int wr = wave >> 1, wc = wave & 1, g = lane >> 4, c = lane & 15;
  f4v acc[4][4] = {};
  gemm128_core(A, Bt, m0, n0, As, Bs, acc);
  #pragma unroll
  for (int mi=0;mi<4;mi++)
    #pragma unroll
    for (int ni=0;ni<4;ni++){
      int col = n0 + wc*64 + ni*16 + c;
      float bi = bias[col];
      #pragma unroll
      for (int i=0;i<4;i++){
        int row = m0 + wr*64 + mi*16 + g*4 + i;
        C[(size_t)row*1024 + col] = acc[mi][ni][i] + bi;
      }
    }
}

// ---- fused attn: S^T scores (reg-resident) + rel bias + entmax1.5 Newton (theta-fold) + PV + rel-ctx MFMA ----
#define ATPAD 1028
__global__ __launch_bounds__(256,4) void attn_fused_k(const short* __restrict__ Qb, const short* __restrict__ Kb,
                                                      const short* __restrict__ relb, const short* __restrict__ relT,
                                                      const short* __restrict__ Vt, short* __restrict__ ctxb){
  __shared__ __align__(16) short pb_b[16][66];       // q.rel^T bf16; later aliased as reduce scratch
  __shared__ __align__(16) float wrow[16][68];       // bucket weights f32
  __shared__ __align__(16) short attn_l[16][ATPAD];  // attn row-major bf16
  float2* red = (float2*)&pb_b[0][0];

  int lane = threadIdx.x & 63, wave = threadIdx.x >> 6;
  int g = lane >> 4, c = lane & 15;
  int flat = blockIdx.x;                              // 2048
  int swz = (flat & 7)*256 + (flat >> 3);             // XCD chunks: 4 heads per XCD chunk
  int bh = swz >> 6, q0 = (swz & 63)*16;
  const short* Qh = Qb + (size_t)bh*65536;
  const short* Kh = Kb + (size_t)bh*65536;
  const short* Vh = Vt + (size_t)bh*65536;

  for (int e = threadIdx.x; e < 16*68; e += 256) ((float*)wrow)[e] = 0.f;

  // Q fragment (16 rows q0..q0+15)
  s8v qa0 = *(const s8v*)(Qh + (q0+c)*64 + g*8);
  s8v qa1 = *(const s8v*)(Qh + (q0+c)*64 + 32 + g*8);

  // pb[r][j] = q_row(r) . rel_emb[j] via MFMA
  {
    int ntile = (wave==3) ? 2 : 1;
    for (int t=0; t<ntile; t++){
      int jt = (t==0) ? wave : 4;
      int j = jt*16 + c;
      s8v rb0 = {}, rb1 = {};
      if (j < 65){
        rb0 = *(const s8v*)(relb + j*64 + g*8);
        rb1 = *(const s8v*)(relb + j*64 + 32 + g*8);
      }
      f4v pa = {};
      pa = __builtin_amdgcn_mfma_f32_16x16x32_bf16(qa0, rb0, pa, 0,0,0);
      pa = __builtin_amdgcn_mfma_f32_16x16x32_bf16(qa1, rb1, pa, 0,0,0);
      if (j < 65){
        #pragma unroll
        for (int i=0;i<4;i++) pb_b[g*4+i][j] = f2bf(pa[i]);
      }
    }
  }
  __syncthreads();

  // scores^T: lane (g,c) holds S[q0+c][k], k = kc0 + t*16 + g*4 + i; pb as C-init
  int q = q0 + c;
  int kc0 = wave*256;
  f4v x[16];
  #pragma unroll
  for (int t=0;t<16;t++){
    f4v ini;
    #pragma unroll
    for (int i=0;i<4;i++){
      int k = kc0 + t*16 + g*4 + i;
      int jj = min(max(k - q, -32), 32) + 32;
      ini[i] = bf2f(pb_b[c][jj]);
    }
    const short* kp = Kh + (kc0 + t*16 + c)*64 + g*8;
    s8v ka0 = *(const s8v*)(kp);
    s8v ka1 = *(const s8v*)(kp + 32);
    ini = __builtin_amdgcn_mfma_f32_16x16x32_bf16(ka0, qa0, ini, 0,0,0);
    x[t] = __builtin_amdgcn_mfma_f32_16x16x32_bf16(ka1, qa1, ini, 0,0,0);
  }
  __syncthreads();   // pb_b dead from here; red alias safe

  // row max (raw scores)
  float m0v = -1e30f, m1v = -1e30f, m2v = -1e30f, m3v = -1e30f;
  #pragma unroll
  for (int t=0;t<16;t++){
    m0v = fmaxf(m0v, x[t][0]); m1v = fmaxf(m1v, x[t][1]);
    m2v = fmaxf(m2v, x[t][2]); m3v = fmaxf(m3v, x[t][3]);
  }
  float mx = fmaxf(fmaxf(m0v,m1v), fmaxf(m2v,m3v));
  mx = fmaxf(mx, __shfl_xor(mx, 16, 64));
  mx = fmaxf(mx, __shfl_xor(mx, 32, 64));
  if (g == 0) red[wave*16 + c] = make_float2(mx, 0.f);
  __syncthreads();
  {
    float2 r0 = red[c], r1 = red[16+c], r2 = red[32+c], r3 = red[48+c];
    mx = fmaxf(fmaxf(r0.x, r1.x), fmaxf(r2.x, r3.x));
  }

  // theta-fold Newton: theta = mx + 2*tau, u = x - theta (true t = u/2)
  // g(tau)=Sum((x'-tau)_+^2)-1 -> theta += (S2u - 4)/(2*S1u); monotone from theta0 = mx-2
  float theta = mx - 2.0f;
  for (int it=0; it<7; it++){
    float s1a=0.f,s1b=0.f,s1c=0.f,s1d=0.f, s2a=0.f,s2b=0.f,s2c=0.f,s2d=0.f;
    #pragma unroll
    for (int t=0;t<16;t++){
      float t0 = fmaxf(x[t][0]-theta, 0.f); s1a += t0; s2a = fmaf(t0,t0,s2a);
      float t1 = fmaxf(x[t][1]-theta, 0.f); s1b += t1; s2b = fmaf(t1,t1,s2b);
      float t2 = fmaxf(x[t][2]-theta, 0.f); s1c += t2; s2c = fmaf(t2,t2,s2c);
      float t3 = fmaxf(x[t][3]-theta, 0.f); s1d += t3; s2d = fmaf(t3,t3,s2d);
    }
    float S1 = (s1a+s1b)+(s1c+s1d), S2 = (s2a+s2b)+(s2c+s2d);
    S1 += __shfl_xor(S1, 16, 64); S2 += __shfl_xor(S2, 16, 64);
    S1 += __shfl_xor(S1, 32, 64); S2 += __shfl_xor(S2, 32, 64);
    int pp = (it+1)&1;
    if (g == 0) red[(pp*4 + wave)*16 + c] = make_float2(S1, S2);
    __syncthreads();
    float2 r0 = red[pp*64 + c], r1 = red[pp*64 + 16+c], r2 = red[pp*64 + 32+c], r3 = red[pp*64 + 48+c];
    S1 = (r0.x+r1.x)+(r2.x+r3.x);
    S2 = (r0.y+r1.y)+(r2.y+r3.y);
    theta += (S2 - 4.0f)/(2.0f*S1);
  }

  // epilogue: attn bf16 -> LDS (packed b64), bucket weights
  float w0p = 0.f, w64p = 0.f;
  #pragma unroll
  for (int t=0;t<16;t++){
    s4v pk;
    #pragma unroll
    for (int i=0;i<4;i++){
      int k = kc0 + t*16 + g*4 + i;
      float tt = fmaxf(x[t][i]-theta, 0.f)*0.5f;
      float a = tt*tt;
      pk[i] = f2bf(a);
      int raw = k - q;
      if (raw <= -32) w0p += a;
      else if (raw >= 32) w64p += a;
      else wrow[c][raw+32] = a;   // unique (q,k) owner
    }
    *(s4v*)(&attn_l[c][kc0 + t*16 + g*4]) = pk;
  }
  w0p += __shfl_xor(w0p, 16, 64); w64p += __shfl_xor(w64p, 16, 64);
  w0p += __shfl_xor(w0p, 32, 64); w64p += __shfl_xor(w64p, 32, 64);
  if (g == 0) red[wave*16 + c] = make_float2(w0p, w64p);
  __syncthreads();
  if (wave == 0 && g == 0){
    float2 r0 = red[c], r1 = red[16+c], r2 = red[32+c], r3 = red[48+c];
    wrow[c][0]  = (r0.x+r1.x)+(r2.x+r3.x);
    wrow[c][64] = (r0.y+r1.y)+(r2.y+r3.y);
  }
  __syncthreads();

  // PV: wave owns d-cols [wave*16,+16), full K=1024; + rel-ctx via 2 MFMAs
  f4v acc = {};
  #pragma unroll 8
  for (int kk=0; kk<32; kk++){
    s8v af = *(const s8v*)(&attn_l[c][kk*32 + g*8]);
    s8v bf = *(const s8v*)(Vh + (size_t)(wave*16+c)*1024 + kk*32 + g*8);
    acc = __builtin_amdgcn_mfma_f32_16x16x32_bf16(af, bf, acc, 0,0,0);
  }
  {
    const float* wp = &wrow[c][0];
    f4v a_ = *(const f4v*)(wp + g*8);
    f4v b_ = *(const f4v*)(wp + g*8 + 4);
    f4v c_ = *(const f4v*)(wp + 32 + g*8);
    f4v d_ = *(const f4v*)(wp + 32 + g*8 + 4);
    s8v wa0, wa1;
    wa0[0]=f2bf(a_[0]); wa0[1]=f2bf(a_[1]); wa0[2]=f2bf(a_[2]); wa0[3]=f2bf(a_[3]);
    wa0[4]=f2bf(b_[0]); wa0[5]=f2bf(b_[1]); wa0[6]=f2bf(b_[2]); wa0[7]=f2bf(b_[3]);
    wa1[0]=f2bf(c_[0]); wa1[1]=f2bf(c_[1]); wa1[2]=f2bf(c_[2]); wa1[3]=f2bf(c_[3]);
    wa1[4]=f2bf(d_[0]); wa1[5]=f2bf(d_[1]); wa1[6]=f2bf(d_[2]); wa1[7]=f2bf(d_[3]);
    s8v rb0 = *(const s8v*)(relT + (wave*16+c)*72 + g*8);
    s8v rb1 = *(const s8v*)(relT + (wave*16+c)*72 + 32 + g*8);
    acc = __builtin_amdgcn_mfma_f32_16x16x32_bf16(wa0, rb0, acc, 0,0,0);
    acc = __builtin_amdgcn_mfma_f32_16x16x32_bf16(wa1, rb1, acc, 0,0,0);
  }
  int b = bh >> 4, h = bh & 15, d = wave*16 + c;
  float rl64 = bf2f(relT[d*72 + 64]);
  #pragma unroll
  for (int i=0;i<4;i++){
    int r = g*4+i;
    float s = acc[i] + wrow[r][64]*rl64;
    ctxb[((size_t)(b*1024 + q0 + r))*1024 + h*64 + d] = f2bf(s);
  }
}

extern "C" void kernel_launch(void* const* d_in, const int* in_sizes, int n_in,
                              void* d_out, int out_size, void* d_ws, size_t ws_size,
                              hipStream_t stream) {
  (void)in_sizes; (void)n_in; (void)out_size; (void)ws_size;
  const float* x    = (const float*)d_in[0];
  const float* w_q  = (const float*)d_in[1];
  const float* b_q  = (const float*)d_in[2];
  const float* w_k  = (const float*)d_in[3];
  const float* b_k  = (const float*)d_in[4];
  const float* w_v  = (const float*)d_in[5];
  const float* b_v  = (const float*)d_in[6];
  const float* w_o  = (const float*)d_in[7];
  const float* b_o  = (const float*)d_in[8];
  const float* rel  = (const float*)d_in[9];
  const float* rcos = (const float*)d_in[10];
  const float* rsin = (const float*)d_in[11];
  float* out = (float*)d_out;

  char* w = (char*)d_ws;
  short* xb    = (short*)(w);                        // 4 MiB
  short* wqkvT = (short*)(w + ((size_t)4<<20));      // 6 MiB  [3072][1024]
  short* woT   = (short*)(w + ((size_t)10<<20));     // 2 MiB
  short* Qb    = (short*)(w + ((size_t)12<<20));     // 4 MiB
  short* Kb    = (short*)(w + ((size_t)16<<20));     // 4 MiB
  short* Vt    = (short*)(w + ((size_t)20<<20));     // 4 MiB
  short* ctxb  = (short*)(w + ((size_t)24<<20));     // 4 MiB
  short* relb  = (short*)(w + ((size_t)28<<20));     // 8.3 KB
  short* relT  = (short*)(w + ((size_t)28<<20) + 65536); // 9.2 KB

  prep_k<<<dim3(16,16,6), 256, 0, stream>>>(w_q, w_k, w_v, w_o, x, rel, wqkvT, woT, xb, relb, relT);
  gemm_qkv_k<<<384, 256, 0, stream>>>(xb, wqkvT, b_q, b_k, b_v, rcos, rsin, Qb, Kb, Vt);
  attn_fused_k<<<2048, 256, 0, stream>>>(Qb, Kb, relb, relT, Vt, ctxb);
  gemm_out_k<<<128, 256, 0, stream>>>(ctxb, woT, b_o, out);
}